// Round 16
// baseline (305.053 us; speedup 1.0000x reference)
//
#include <hip/hip_runtime.h>

#define BB 16
#define HH 256
#define WW 256

typedef int i32x4 __attribute__((ext_vector_type(4)));
typedef int i32x16 __attribute__((ext_vector_type(16)));
typedef float f32x16 __attribute__((ext_vector_type(16)));
typedef _Float16 f16x8 __attribute__((ext_vector_type(8)));

// ================= fused prep =================
__global__ __launch_bounds__(256) void prep_kernel(
    const float* __restrict__ x, const float* __restrict__ w1,
    const float* __restrict__ w2, const float* __restrict__ w3,
    const float* __restrict__ w4, const float* __restrict__ w5,
    const float* __restrict__ w6, const float* __restrict__ w7,
    const float* __restrict__ wfc,
    _Float16* __restrict__ pre, _Float16* __restrict__ frag1,
    signed char* __restrict__ wfr, int* __restrict__ wfcq,
    int* __restrict__ gmax) {
  int bid = blockIdx.x, tid = threadIdx.x;
  if (bid < 4096) {
    int px = bid * 256 + tid;  // 1,048,576 pixels
    int b = px >> 16, rem = px & 65535;
    const float* xp = x + (size_t)b * 4 * 65536 + rem;
    f16x8 o;
#pragma unroll
    for (int ic = 0; ic < 4; ++ic) {
      float v = xp[ic * 65536];
      _Float16 hf = (_Float16)v;
      float r = v - (float)hf;
      o[ic * 2] = hf;
      o[ic * 2 + 1] = (_Float16)r;
    }
    *(f16x8*)(pre + (size_t)px * 8) = o;
  } else if (bid < 4312) {
    int i = (bid - 4096) * 256 + tid;  // 6 x 9216
    int layer = i / 9216, within = i - layer * 9216;
    const float* w = layer == 0 ? w2 : layer == 1 ? w3 : layer == 2 ? w4
                   : layer == 3 ? w5 : layer == 4 ? w6 : w7;
    int t = within >> 10;
    int l = (within >> 4) & 63;
    int j = within & 15;
    int ic = (l >> 5) * 16 + j;
    int oc = l & 31;
    int q = (int)rintf(w[oc * 288 + ic * 9 + t] * 128.0f);
    q = min(127, max(-127, q));
    wfr[(size_t)layer * 9216 + within] = (signed char)q;
  } else {
    // conv1 f16 B-frags
    for (int p = tid; p < 384; p += 256) {
      int s = p >> 6, l = p & 63;
      int dr = s >> 1, pp = s & 1;
      int oc = l & 31, half = l >> 5;
      int dx = pp * 2 + half;
#pragma unroll
      for (int j = 0; j < 8; ++j) {
        int ic = j >> 1;
        _Float16 v = (_Float16)0.f;
        if (!(pp == 1 && half == 1)) {
          int q = (int)rintf(w1[oc * 36 + ic * 9 + dr * 3 + dx] * 128.0f);
          q = min(127, max(-127, q));
          v = (_Float16)((float)q * 0.0078125f);  // exact in fp16
        }
        frag1[s * 512 + l * 8 + j] = v;
      }
    }
    if (tid < 32) {
      int q = (int)rintf(wfc[tid] * 128.0f);
      q = min(127, max(-127, q));
      wfcq[tid] = q;
    }
    for (int i2 = tid; i2 < 512; i2 += 256) gmax[i2] = -128;
  }
}

// ================= conv1: f16 hi/lo implicit-GEMM MFMA =================
__global__ __launch_bounds__(256) void conv1_mfma_kernel(
    const _Float16* __restrict__ pre, const _Float16* __restrict__ frag1,
    signed char* __restrict__ out) {
  int tid = threadIdx.x;
  int wi = tid >> 6;
  int l = tid & 63;
  int lo = l & 31;
  int hi = l >> 5;
  int b = blockIdx.z;
  int h0 = blockIdx.y * 2;
  int wbase = blockIdx.x * 128 + wi * 32;
  int w = wbase + lo;

  const f16x8* fp = (const f16x8*)frag1;
  f16x8 bf[6];
#pragma unroll
  for (int s = 0; s < 6; ++s) bf[s] = fp[s * 64 + l];

  f32x16 acc0 = {}, acc1 = {};
  const size_t img = (size_t)b * (HH * WW);

#pragma unroll
  for (int r = 0; r < 4; ++r) {  // input rows h0-1 .. h0+2
    int yy = h0 - 1 + r;
    bool okr = (unsigned)yy < 256u;
#pragma unroll
    for (int p = 0; p < 2; ++p) {
      int xx = w + p * 2 + hi - 1;  // dx = 2p + half
      f16x8 av = {};
      if (okr && !(p == 1 && hi == 1) && ((unsigned)xx < 256u))
        av = *(const f16x8*)(pre + ((img + (size_t)yy * WW + xx) << 3));
      if (r < 3) acc0 = __builtin_amdgcn_mfma_f32_32x32x16_f16(av, bf[r * 2 + p], acc0, 0, 0, 0);
      if (r > 0) acc1 = __builtin_amdgcn_mfma_f32_32x32x16_f16(av, bf[(r - 1) * 2 + p], acc1, 0, 0, 0);
    }
  }

  signed char* op = out + ((img + (size_t)h0 * WW + wbase) << 5) + lo;
#pragma unroll
  for (int r = 0; r < 16; ++r) {
    int row = (r & 3) + 8 * (r >> 2) + 4 * hi;
    int q0 = (int)rintf(acc0[r] * 128.0f);
    q0 = min(127, max(-127, q0));
    op[row * 32] = (signed char)q0;
    int q1 = (int)rintf(acc1[r] * 128.0f);
    q1 = min(127, max(-127, q1));
    op[WW * 32 + row * 32] = (signed char)q1;
  }
}

// ================= fused mid groups =================
// Exact integer RNE: rne(a/128) = (a + 63 + ((a>>7)&1)) >> 7, proven for all
// residues/parities/signs (bit-identical to the verified rintf path).
__device__ __forceinline__ int quant1(int a) {
  int q = (a + 63 + ((a >> 7) & 1)) >> 7;
  return min(127, max(-127, q));  // -> v_med3_i32
}

__device__ __forceinline__ int quant_max(const i32x16& acc, int mymax) {
#pragma unroll
  for (int r = 0; r < 16; ++r) mymax = max(mymax, quant1(acc[r]));
  return mymax;
}

__device__ __forceinline__ int pack4(int q0, int q1, int q2, int q3) {
  return (q0 & 255) | ((q1 & 255) << 8) | ((q2 & 255) << 16) | ((q3 & 255) << 24);
}

// Two conv layers fused; 3 layer-B output rows per block (5 A-rows in LDS).
// LDS ~50KB -> 3 blocks/CU (24 waves/CU) for latency hiding.
// Lint layout [rrel 0..4][half][px] in 16B units (phase-2 taps stream b128).
// MODE 0: layer B stores to global (lane owns px). MODE 1: per-oc max only.
template <int MODE>
__global__ __launch_bounds__(512, 6) void conv_fused_kernel(
    const signed char* __restrict__ in, const signed char* __restrict__ fragA,
    const signed char* __restrict__ fragB, signed char* __restrict__ out,
    int* __restrict__ gmax) {
  __shared__ int Lint[5 * 2 * 256 * 4];  // 40960 B
  __shared__ int lbf[2304];              // 9216 B, A-frags then B-frags
  __shared__ int red[8][32];

  int tid = threadIdx.x;
  int wi = tid >> 6;
  int l = tid & 63;
  int lo = l & 31;
  int hi = l >> 5;
  int b = blockIdx.y;
  int hs = blockIdx.x * 3;  // layer-B output rows hs..hs+2 (hs <= 255)
  int w = wi * 32 + lo;     // this lane's pixel column
  const size_t img = (size_t)b * (HH * WW);

  const int* fA32 = (const int*)fragA;
  for (int i = tid; i < 2304; i += 512) lbf[i] = fA32[i];
  __syncthreads();

  auto ldrow = [&](int yy, int dx) -> i32x4 {
    i32x4 r = {};
    int xx = w + dx - 1;
    if (((unsigned)yy < 256u) && ((unsigned)xx < 256u))
      r = *(const i32x4*)(in + ((img + (size_t)yy * WW + xx) << 5) + hi * 16);
    return r;
  };

  // ---- phase 1: layer A rows hs-1..hs+3 (rrel 0..4): 2 pairs + 1 single ----
#pragma unroll 1
  for (int p = 0; p < 2; ++p) {
    int ar0 = hs - 1 + 2 * p;  // first A-output row of this pair
    i32x4 rin[4][3];
#pragma unroll
    for (int rr = 0; rr < 4; ++rr)
#pragma unroll
      for (int dx = 0; dx < 3; ++dx)
        rin[rr][dx] = ldrow(ar0 - 1 + rr, dx);

    int pz = 0;
    asm volatile("" : "+v"(pz));  // force per-pair LDS weight re-read
    i32x16 acc0 = {}, acc1 = {};
#pragma unroll
    for (int t = 0; t < 9; ++t) {
      int dy = t / 3, dx = t % 3;
      i32x4 bfv = *(const i32x4*)&lbf[(t * 64 + l) * 4 + pz];
      acc0 = __builtin_amdgcn_mfma_i32_32x32x32_i8(bfv, rin[dy][dx], acc0, 0, 0, 0);
      acc1 = __builtin_amdgcn_mfma_i32_32x32x32_i8(bfv, rin[dy + 1][dx], acc1, 0, 0, 0);
    }
#pragma unroll
    for (int g = 0; g < 4; ++g) {
      int d = 2 * g + hi;
      int v0 = pack4(quant1(acc0[4 * g]), quant1(acc0[4 * g + 1]),
                     quant1(acc0[4 * g + 2]), quant1(acc0[4 * g + 3]));
      int v1 = pack4(quant1(acc1[4 * g]), quant1(acc1[4 * g + 1]),
                     quant1(acc1[4 * g + 2]), quant1(acc1[4 * g + 3]));
      Lint[(((2 * p) * 2 + (d >> 2)) * 256 + w) * 4 + (d & 3)] = v0;
      Lint[(((2 * p + 1) * 2 + (d >> 2)) * 256 + w) * 4 + (d & 3)] = v1;
    }
  }
  {  // single A-row rrel 4 (row hs+3)
    int ar = hs + 3;
    i32x4 rin[3][3];
#pragma unroll
    for (int rr = 0; rr < 3; ++rr)
#pragma unroll
      for (int dx = 0; dx < 3; ++dx)
        rin[rr][dx] = ldrow(ar - 1 + rr, dx);
    int pz = 0;
    asm volatile("" : "+v"(pz));
    i32x16 acc0 = {};
#pragma unroll
    for (int t = 0; t < 9; ++t) {
      int dy = t / 3, dx = t % 3;
      i32x4 bfv = *(const i32x4*)&lbf[(t * 64 + l) * 4 + pz];
      acc0 = __builtin_amdgcn_mfma_i32_32x32x32_i8(bfv, rin[dy][dx], acc0, 0, 0, 0);
    }
#pragma unroll
    for (int g = 0; g < 4; ++g) {
      int d = 2 * g + hi;
      int v0 = pack4(quant1(acc0[4 * g]), quant1(acc0[4 * g + 1]),
                     quant1(acc0[4 * g + 2]), quant1(acc0[4 * g + 3]));
      Lint[((4 * 2 + (d >> 2)) * 256 + w) * 4 + (d & 3)] = v0;
    }
  }

  __syncthreads();
  const int* fB32 = (const int*)fragB;
  for (int i = tid; i < 2304; i += 512) lbf[i] = fB32[i];
  __syncthreads();

  // ---- phase 2: layer B rows hs, hs+1 (pair) + hs+2 (single) from LDS ----
  int mymax = -128;
  bool ok1 = (hs + 1) < 256;
  bool ok2 = (hs + 2) < 256;
  {
    i32x4 tp[4][3];
#pragma unroll
    for (int rr = 0; rr < 4; ++rr) {
      int aro = hs - 1 + rr;  // absolute layer-A row (rrel rr)
#pragma unroll
      for (int dx = 0; dx < 3; ++dx) {
        int px = w + dx - 1;
        i32x4 v = {};
        if (((unsigned)aro < 256u) && ((unsigned)px < 256u))
          v = *(const i32x4*)&Lint[((rr * 2 + hi) * 256 + px) * 4];
        tp[rr][dx] = v;
      }
    }
    int pz = 0;
    asm volatile("" : "+v"(pz));
    i32x16 acc0 = {}, acc1 = {};
#pragma unroll
    for (int t = 0; t < 9; ++t) {
      int dy = t / 3, dx = t % 3;
      i32x4 bfv = *(const i32x4*)&lbf[(t * 64 + l) * 4 + pz];
      if (MODE == 1) {
        acc0 = __builtin_amdgcn_mfma_i32_32x32x32_i8(tp[dy][dx], bfv, acc0, 0, 0, 0);
        acc1 = __builtin_amdgcn_mfma_i32_32x32x32_i8(tp[dy + 1][dx], bfv, acc1, 0, 0, 0);
      } else {
        acc0 = __builtin_amdgcn_mfma_i32_32x32x32_i8(bfv, tp[dy][dx], acc0, 0, 0, 0);
        acc1 = __builtin_amdgcn_mfma_i32_32x32x32_i8(bfv, tp[dy + 1][dx], acc1, 0, 0, 0);
      }
    }
    if (MODE == 0) {
      int* o32 = (int*)out;
      size_t base = (img + (size_t)hs * WW + w) * 8;
#pragma unroll
      for (int g = 0; g < 4; ++g) {
        int v0 = pack4(quant1(acc0[4 * g]), quant1(acc0[4 * g + 1]),
                       quant1(acc0[4 * g + 2]), quant1(acc0[4 * g + 3]));
        o32[base + 2 * g + hi] = v0;
        if (ok1) {
          int v1 = pack4(quant1(acc1[4 * g]), quant1(acc1[4 * g + 1]),
                         quant1(acc1[4 * g + 2]), quant1(acc1[4 * g + 3]));
          o32[base + 2048 + 2 * g + hi] = v1;
        }
      }
    } else {
      mymax = quant_max(acc0, mymax);
      if (ok1) mymax = quant_max(acc1, mymax);
    }
  }
  {  // single B-row hs+2 (reads rrel 2..4)
    i32x4 tp[3][3];
#pragma unroll
    for (int rr = 0; rr < 3; ++rr) {
      int aro = hs + 1 + rr;
#pragma unroll
      for (int dx = 0; dx < 3; ++dx) {
        int px = w + dx - 1;
        i32x4 v = {};
        if (((unsigned)aro < 256u) && ((unsigned)px < 256u))
          v = *(const i32x4*)&Lint[(((rr + 2) * 2 + hi) * 256 + px) * 4];
        tp[rr][dx] = v;
      }
    }
    int pz = 0;
    asm volatile("" : "+v"(pz));
    i32x16 acc0 = {};
#pragma unroll
    for (int t = 0; t < 9; ++t) {
      int dy = t / 3, dx = t % 3;
      i32x4 bfv = *(const i32x4*)&lbf[(t * 64 + l) * 4 + pz];
      if (MODE == 1)
        acc0 = __builtin_amdgcn_mfma_i32_32x32x32_i8(tp[dy][dx], bfv, acc0, 0, 0, 0);
      else
        acc0 = __builtin_amdgcn_mfma_i32_32x32x32_i8(bfv, tp[dy][dx], acc0, 0, 0, 0);
    }
    if (MODE == 0) {
      if (ok2) {
        int* o32 = (int*)out;
        size_t base = (img + (size_t)(hs + 2) * WW + w) * 8;
#pragma unroll
        for (int g = 0; g < 4; ++g) {
          int v0 = pack4(quant1(acc0[4 * g]), quant1(acc0[4 * g + 1]),
                         quant1(acc0[4 * g + 2]), quant1(acc0[4 * g + 3]));
          o32[base + 2 * g + hi] = v0;
        }
      }
    } else {
      if (ok2) mymax = quant_max(acc0, mymax);
    }
  }

  if (MODE == 1) {
    mymax = max(mymax, __shfl_xor(mymax, 32));  // lanes lo & lo+32: same oc
    if (hi == 0) red[wi][lo] = mymax;
    __syncthreads();
    if (tid < 32) {
      int m = -128;
#pragma unroll
      for (int r = 0; r < 8; ++r) m = max(m, red[r][tid]);
      atomicMax(&gmax[b * 32 + tid], m);
    }
  }
}

// ================= final FC =================
__global__ void fc_kernel(const int* __restrict__ gmax, const int* __restrict__ wfcq,
                          float* __restrict__ out) {
  int b = threadIdx.x;
  if (b < BB) {
    int acc = 0;
#pragma unroll
    for (int c = 0; c < 32; ++c) acc += gmax[b * 32 + c] * wfcq[c];
    int q = (acc + 63 + ((acc >> 7) & 1)) >> 7;  // rne(acc/128), exact
    q = min(127, max(-127, q));
    out[b] = (float)q * 0.0078125f;
  }
}

extern "C" void kernel_launch(void* const* d_in, const int* in_sizes, int n_in,
                              void* d_out, int out_size, void* d_ws, size_t ws_size,
                              hipStream_t stream) {
  const float* x   = (const float*)d_in[0];
  const float* w1  = (const float*)d_in[1];
  const float* wfc = (const float*)d_in[8];

  char* ws = (char*)d_ws;
  const size_t ACTB = (size_t)BB * HH * WW * 32;  // 33,554,432 B
  signed char* A0    = (signed char*)ws;
  signed char* A1    = (signed char*)(ws + ACTB);
  _Float16*    pre   = (_Float16*)A1;  // dead before F0 writes A1
  _Float16*    frag1 = (_Float16*)(ws + 2 * ACTB);                 // 6144 B
  signed char* wfr   = (signed char*)(ws + 2 * ACTB + 6144);       // 6 x 9216
  int*         wfcq  = (int*)(ws + 2 * ACTB + 6144 + 6 * 9216);
  int*         gmax  = (int*)(ws + 2 * ACTB + 6144 + 6 * 9216 + 128);

  prep_kernel<<<4313, 256, 0, stream>>>(
      x, w1, (const float*)d_in[2], (const float*)d_in[3], (const float*)d_in[4],
      (const float*)d_in[5], (const float*)d_in[6], (const float*)d_in[7],
      wfc, pre, frag1, wfr, wfcq, gmax);

  dim3 gridc1(2, 128, 16);  // conv1: 2-row pairs
  conv1_mfma_kernel<<<gridc1, 256, 0, stream>>>(pre, frag1, A0);

  dim3 gf(86, 16);  // fused pairs: 3-row chunks (86*3 >= 256), full width
  conv_fused_kernel<0><<<gf, 512, 0, stream>>>(A0, wfr + 0 * 9216, wfr + 1 * 9216, A1, nullptr);
  conv_fused_kernel<0><<<gf, 512, 0, stream>>>(A1, wfr + 2 * 9216, wfr + 3 * 9216, A0, nullptr);
  conv_fused_kernel<1><<<gf, 512, 0, stream>>>(A0, wfr + 4 * 9216, wfr + 5 * 9216, nullptr, gmax);
  fc_kernel<<<1, 64, 0, stream>>>(gmax, wfcq, (float*)d_out);
}

// Round 17
// 203.508 us; speedup vs baseline: 1.4990x; 1.4990x over previous
//
#include <hip/hip_runtime.h>

#define BB 16
#define HH 256
#define WW 256

typedef int i32x4 __attribute__((ext_vector_type(4)));
typedef int i32x16 __attribute__((ext_vector_type(16)));
typedef float f32x16 __attribute__((ext_vector_type(16)));
typedef _Float16 f16x8 __attribute__((ext_vector_type(8)));

// ================= fused prep =================
__global__ __launch_bounds__(256) void prep_kernel(
    const float* __restrict__ x, const float* __restrict__ w1,
    const float* __restrict__ w2, const float* __restrict__ w3,
    const float* __restrict__ w4, const float* __restrict__ w5,
    const float* __restrict__ w6, const float* __restrict__ w7,
    const float* __restrict__ wfc,
    _Float16* __restrict__ pre, _Float16* __restrict__ frag1,
    signed char* __restrict__ wfr, int* __restrict__ wfcq,
    int* __restrict__ gmax) {
  int bid = blockIdx.x, tid = threadIdx.x;
  if (bid < 4096) {
    int px = bid * 256 + tid;  // 1,048,576 pixels
    int b = px >> 16, rem = px & 65535;
    const float* xp = x + (size_t)b * 4 * 65536 + rem;
    f16x8 o;
#pragma unroll
    for (int ic = 0; ic < 4; ++ic) {
      float v = xp[ic * 65536];
      _Float16 hf = (_Float16)v;
      float r = v - (float)hf;
      o[ic * 2] = hf;
      o[ic * 2 + 1] = (_Float16)r;
    }
    *(f16x8*)(pre + (size_t)px * 8) = o;
  } else if (bid < 4312) {
    int i = (bid - 4096) * 256 + tid;  // 6 x 9216
    int layer = i / 9216, within = i - layer * 9216;
    const float* w = layer == 0 ? w2 : layer == 1 ? w3 : layer == 2 ? w4
                   : layer == 3 ? w5 : layer == 4 ? w6 : w7;
    int t = within >> 10;
    int l = (within >> 4) & 63;
    int j = within & 15;
    int ic = (l >> 5) * 16 + j;
    int oc = l & 31;
    int q = (int)rintf(w[oc * 288 + ic * 9 + t] * 128.0f);
    q = min(127, max(-127, q));
    wfr[(size_t)layer * 9216 + within] = (signed char)q;
  } else {
    // conv1 f16 B-frags
    for (int p = tid; p < 384; p += 256) {
      int s = p >> 6, l = p & 63;
      int dr = s >> 1, pp = s & 1;
      int oc = l & 31, half = l >> 5;
      int dx = pp * 2 + half;
#pragma unroll
      for (int j = 0; j < 8; ++j) {
        int ic = j >> 1;
        _Float16 v = (_Float16)0.f;
        if (!(pp == 1 && half == 1)) {
          int q = (int)rintf(w1[oc * 36 + ic * 9 + dr * 3 + dx] * 128.0f);
          q = min(127, max(-127, q));
          v = (_Float16)((float)q * 0.0078125f);  // exact in fp16
        }
        frag1[s * 512 + l * 8 + j] = v;
      }
    }
    if (tid < 32) {
      int q = (int)rintf(wfc[tid] * 128.0f);
      q = min(127, max(-127, q));
      wfcq[tid] = q;
    }
    for (int i2 = tid; i2 < 512; i2 += 256) gmax[i2] = -128;
  }
}

// ================= conv1: f16 hi/lo implicit-GEMM MFMA =================
__global__ __launch_bounds__(256) void conv1_mfma_kernel(
    const _Float16* __restrict__ pre, const _Float16* __restrict__ frag1,
    signed char* __restrict__ out) {
  int tid = threadIdx.x;
  int wi = tid >> 6;
  int l = tid & 63;
  int lo = l & 31;
  int hi = l >> 5;
  int b = blockIdx.z;
  int h0 = blockIdx.y * 2;
  int wbase = blockIdx.x * 128 + wi * 32;
  int w = wbase + lo;

  const f16x8* fp = (const f16x8*)frag1;
  f16x8 bf[6];
#pragma unroll
  for (int s = 0; s < 6; ++s) bf[s] = fp[s * 64 + l];

  f32x16 acc0 = {}, acc1 = {};
  const size_t img = (size_t)b * (HH * WW);

#pragma unroll
  for (int r = 0; r < 4; ++r) {  // input rows h0-1 .. h0+2
    int yy = h0 - 1 + r;
    bool okr = (unsigned)yy < 256u;
#pragma unroll
    for (int p = 0; p < 2; ++p) {
      int xx = w + p * 2 + hi - 1;  // dx = 2p + half
      f16x8 av = {};
      if (okr && !(p == 1 && hi == 1) && ((unsigned)xx < 256u))
        av = *(const f16x8*)(pre + ((img + (size_t)yy * WW + xx) << 3));
      if (r < 3) acc0 = __builtin_amdgcn_mfma_f32_32x32x16_f16(av, bf[r * 2 + p], acc0, 0, 0, 0);
      if (r > 0) acc1 = __builtin_amdgcn_mfma_f32_32x32x16_f16(av, bf[(r - 1) * 2 + p], acc1, 0, 0, 0);
    }
  }

  signed char* op = out + ((img + (size_t)h0 * WW + wbase) << 5) + lo;
#pragma unroll
  for (int r = 0; r < 16; ++r) {
    int row = (r & 3) + 8 * (r >> 2) + 4 * hi;
    int q0 = (int)rintf(acc0[r] * 128.0f);
    q0 = min(127, max(-127, q0));
    op[row * 32] = (signed char)q0;
    int q1 = (int)rintf(acc1[r] * 128.0f);
    q1 = min(127, max(-127, q1));
    op[WW * 32 + row * 32] = (signed char)q1;
  }
}

// ================= fused mid groups =================
// Exact integer RNE: rne(a/128) = (a + 63 + ((a>>7)&1)) >> 7, proven for all
// residues/parities/signs (bit-identical to the verified rintf path).
__device__ __forceinline__ int quant1(int a) {
  int q = (a + 63 + ((a >> 7) & 1)) >> 7;
  return min(127, max(-127, q));  // -> v_med3_i32
}

__device__ __forceinline__ int quant_max(const i32x16& acc, int mymax) {
#pragma unroll
  for (int r = 0; r < 16; ++r) mymax = max(mymax, quant1(acc[r]));
  return mymax;
}

__device__ __forceinline__ int pack4(int q0, int q1, int q2, int q3) {
  return (q0 & 255) | ((q1 & 255) << 8) | ((q2 & 255) << 16) | ((q3 & 255) << 24);
}

// Two conv layers fused; 3 layer-B output rows per block (5 A-rows in LDS).
// LDS 50176 B -> 3 blocks/CU; __launch_bounds__(512,4) keeps the VGPR cap at
// 128 (round 16's (512,6) cap=~85 caused catastrophic scratch spills:
// FETCH 33->88 MB, WRITE 33->121 MB). Round 15 proved (512,4) is spill-free
// at this per-pair register pressure.
// Lint layout [rrel 0..4][half][px] in 16B units (phase-2 taps stream b128).
// MODE 0: layer B stores to global (lane owns px). MODE 1: per-oc max only.
template <int MODE>
__global__ __launch_bounds__(512, 4) void conv_fused_kernel(
    const signed char* __restrict__ in, const signed char* __restrict__ fragA,
    const signed char* __restrict__ fragB, signed char* __restrict__ out,
    int* __restrict__ gmax) {
  __shared__ int Lint[5 * 2 * 256 * 4];  // 40960 B
  __shared__ int lbf[2304];              // 9216 B, A-frags then B-frags
  __shared__ int red[8][32];

  int tid = threadIdx.x;
  int wi = tid >> 6;
  int l = tid & 63;
  int lo = l & 31;
  int hi = l >> 5;
  int b = blockIdx.y;
  int hs = blockIdx.x * 3;  // layer-B output rows hs..hs+2 (hs <= 255)
  int w = wi * 32 + lo;     // this lane's pixel column
  const size_t img = (size_t)b * (HH * WW);

  const int* fA32 = (const int*)fragA;
  for (int i = tid; i < 2304; i += 512) lbf[i] = fA32[i];
  __syncthreads();

  auto ldrow = [&](int yy, int dx) -> i32x4 {
    i32x4 r = {};
    int xx = w + dx - 1;
    if (((unsigned)yy < 256u) && ((unsigned)xx < 256u))
      r = *(const i32x4*)(in + ((img + (size_t)yy * WW + xx) << 5) + hi * 16);
    return r;
  };

  // ---- phase 1: layer A rows hs-1..hs+3 (rrel 0..4): 2 pairs + 1 single ----
#pragma unroll 1
  for (int p = 0; p < 2; ++p) {
    int ar0 = hs - 1 + 2 * p;  // first A-output row of this pair
    i32x4 rin[4][3];
#pragma unroll
    for (int rr = 0; rr < 4; ++rr)
#pragma unroll
      for (int dx = 0; dx < 3; ++dx)
        rin[rr][dx] = ldrow(ar0 - 1 + rr, dx);

    int pz = 0;
    asm volatile("" : "+v"(pz));  // force per-pair LDS weight re-read
    i32x16 acc0 = {}, acc1 = {};
#pragma unroll
    for (int t = 0; t < 9; ++t) {
      int dy = t / 3, dx = t % 3;
      i32x4 bfv = *(const i32x4*)&lbf[(t * 64 + l) * 4 + pz];
      acc0 = __builtin_amdgcn_mfma_i32_32x32x32_i8(bfv, rin[dy][dx], acc0, 0, 0, 0);
      acc1 = __builtin_amdgcn_mfma_i32_32x32x32_i8(bfv, rin[dy + 1][dx], acc1, 0, 0, 0);
    }
#pragma unroll
    for (int g = 0; g < 4; ++g) {
      int d = 2 * g + hi;
      int v0 = pack4(quant1(acc0[4 * g]), quant1(acc0[4 * g + 1]),
                     quant1(acc0[4 * g + 2]), quant1(acc0[4 * g + 3]));
      int v1 = pack4(quant1(acc1[4 * g]), quant1(acc1[4 * g + 1]),
                     quant1(acc1[4 * g + 2]), quant1(acc1[4 * g + 3]));
      Lint[(((2 * p) * 2 + (d >> 2)) * 256 + w) * 4 + (d & 3)] = v0;
      Lint[(((2 * p + 1) * 2 + (d >> 2)) * 256 + w) * 4 + (d & 3)] = v1;
    }
  }
  {  // single A-row rrel 4 (row hs+3)
    int ar = hs + 3;
    i32x4 rin[3][3];
#pragma unroll
    for (int rr = 0; rr < 3; ++rr)
#pragma unroll
      for (int dx = 0; dx < 3; ++dx)
        rin[rr][dx] = ldrow(ar - 1 + rr, dx);
    int pz = 0;
    asm volatile("" : "+v"(pz));
    i32x16 acc0 = {};
#pragma unroll
    for (int t = 0; t < 9; ++t) {
      int dy = t / 3, dx = t % 3;
      i32x4 bfv = *(const i32x4*)&lbf[(t * 64 + l) * 4 + pz];
      acc0 = __builtin_amdgcn_mfma_i32_32x32x32_i8(bfv, rin[dy][dx], acc0, 0, 0, 0);
    }
#pragma unroll
    for (int g = 0; g < 4; ++g) {
      int d = 2 * g + hi;
      int v0 = pack4(quant1(acc0[4 * g]), quant1(acc0[4 * g + 1]),
                     quant1(acc0[4 * g + 2]), quant1(acc0[4 * g + 3]));
      Lint[((4 * 2 + (d >> 2)) * 256 + w) * 4 + (d & 3)] = v0;
    }
  }

  __syncthreads();
  const int* fB32 = (const int*)fragB;
  for (int i = tid; i < 2304; i += 512) lbf[i] = fB32[i];
  __syncthreads();

  // ---- phase 2: layer B rows hs, hs+1 (pair) + hs+2 (single) from LDS ----
  int mymax = -128;
  bool ok1 = (hs + 1) < 256;
  bool ok2 = (hs + 2) < 256;
  {
    i32x4 tp[4][3];
#pragma unroll
    for (int rr = 0; rr < 4; ++rr) {
      int aro = hs - 1 + rr;  // absolute layer-A row (rrel rr)
#pragma unroll
      for (int dx = 0; dx < 3; ++dx) {
        int px = w + dx - 1;
        i32x4 v = {};
        if (((unsigned)aro < 256u) && ((unsigned)px < 256u))
          v = *(const i32x4*)&Lint[((rr * 2 + hi) * 256 + px) * 4];
        tp[rr][dx] = v;
      }
    }
    int pz = 0;
    asm volatile("" : "+v"(pz));
    i32x16 acc0 = {}, acc1 = {};
#pragma unroll
    for (int t = 0; t < 9; ++t) {
      int dy = t / 3, dx = t % 3;
      i32x4 bfv = *(const i32x4*)&lbf[(t * 64 + l) * 4 + pz];
      if (MODE == 1) {
        acc0 = __builtin_amdgcn_mfma_i32_32x32x32_i8(tp[dy][dx], bfv, acc0, 0, 0, 0);
        acc1 = __builtin_amdgcn_mfma_i32_32x32x32_i8(tp[dy + 1][dx], bfv, acc1, 0, 0, 0);
      } else {
        acc0 = __builtin_amdgcn_mfma_i32_32x32x32_i8(bfv, tp[dy][dx], acc0, 0, 0, 0);
        acc1 = __builtin_amdgcn_mfma_i32_32x32x32_i8(bfv, tp[dy + 1][dx], acc1, 0, 0, 0);
      }
    }
    if (MODE == 0) {
      int* o32 = (int*)out;
      size_t base = (img + (size_t)hs * WW + w) * 8;
#pragma unroll
      for (int g = 0; g < 4; ++g) {
        int v0 = pack4(quant1(acc0[4 * g]), quant1(acc0[4 * g + 1]),
                       quant1(acc0[4 * g + 2]), quant1(acc0[4 * g + 3]));
        o32[base + 2 * g + hi] = v0;
        if (ok1) {
          int v1 = pack4(quant1(acc1[4 * g]), quant1(acc1[4 * g + 1]),
                         quant1(acc1[4 * g + 2]), quant1(acc1[4 * g + 3]));
          o32[base + 2048 + 2 * g + hi] = v1;
        }
      }
    } else {
      mymax = quant_max(acc0, mymax);
      if (ok1) mymax = quant_max(acc1, mymax);
    }
  }
  {  // single B-row hs+2 (reads rrel 2..4)
    i32x4 tp[3][3];
#pragma unroll
    for (int rr = 0; rr < 3; ++rr) {
      int aro = hs + 1 + rr;
#pragma unroll
      for (int dx = 0; dx < 3; ++dx) {
        int px = w + dx - 1;
        i32x4 v = {};
        if (((unsigned)aro < 256u) && ((unsigned)px < 256u))
          v = *(const i32x4*)&Lint[(((rr + 2) * 2 + hi) * 256 + px) * 4];
        tp[rr][dx] = v;
      }
    }
    int pz = 0;
    asm volatile("" : "+v"(pz));
    i32x16 acc0 = {};
#pragma unroll
    for (int t = 0; t < 9; ++t) {
      int dy = t / 3, dx = t % 3;
      i32x4 bfv = *(const i32x4*)&lbf[(t * 64 + l) * 4 + pz];
      if (MODE == 1)
        acc0 = __builtin_amdgcn_mfma_i32_32x32x32_i8(tp[dy][dx], bfv, acc0, 0, 0, 0);
      else
        acc0 = __builtin_amdgcn_mfma_i32_32x32x32_i8(bfv, tp[dy][dx], acc0, 0, 0, 0);
    }
    if (MODE == 0) {
      if (ok2) {
        int* o32 = (int*)out;
        size_t base = (img + (size_t)(hs + 2) * WW + w) * 8;
#pragma unroll
        for (int g = 0; g < 4; ++g) {
          int v0 = pack4(quant1(acc0[4 * g]), quant1(acc0[4 * g + 1]),
                         quant1(acc0[4 * g + 2]), quant1(acc0[4 * g + 3]));
          o32[base + 2 * g + hi] = v0;
        }
      }
    } else {
      if (ok2) mymax = quant_max(acc0, mymax);
    }
  }

  if (MODE == 1) {
    mymax = max(mymax, __shfl_xor(mymax, 32));  // lanes lo & lo+32: same oc
    if (hi == 0) red[wi][lo] = mymax;
    __syncthreads();
    if (tid < 32) {
      int m = -128;
#pragma unroll
      for (int r = 0; r < 8; ++r) m = max(m, red[r][tid]);
      atomicMax(&gmax[b * 32 + tid], m);
    }
  }
}

// ================= final FC =================
__global__ void fc_kernel(const int* __restrict__ gmax, const int* __restrict__ wfcq,
                          float* __restrict__ out) {
  int b = threadIdx.x;
  if (b < BB) {
    int acc = 0;
#pragma unroll
    for (int c = 0; c < 32; ++c) acc += gmax[b * 32 + c] * wfcq[c];
    int q = (acc + 63 + ((acc >> 7) & 1)) >> 7;  // rne(acc/128), exact
    q = min(127, max(-127, q));
    out[b] = (float)q * 0.0078125f;
  }
}

extern "C" void kernel_launch(void* const* d_in, const int* in_sizes, int n_in,
                              void* d_out, int out_size, void* d_ws, size_t ws_size,
                              hipStream_t stream) {
  const float* x   = (const float*)d_in[0];
  const float* w1  = (const float*)d_in[1];
  const float* wfc = (const float*)d_in[8];

  char* ws = (char*)d_ws;
  const size_t ACTB = (size_t)BB * HH * WW * 32;  // 33,554,432 B
  signed char* A0    = (signed char*)ws;
  signed char* A1    = (signed char*)(ws + ACTB);
  _Float16*    pre   = (_Float16*)A1;  // dead before F0 writes A1
  _Float16*    frag1 = (_Float16*)(ws + 2 * ACTB);                 // 6144 B
  signed char* wfr   = (signed char*)(ws + 2 * ACTB + 6144);       // 6 x 9216
  int*         wfcq  = (int*)(ws + 2 * ACTB + 6144 + 6 * 9216);
  int*         gmax  = (int*)(ws + 2 * ACTB + 6144 + 6 * 9216 + 128);

  prep_kernel<<<4313, 256, 0, stream>>>(
      x, w1, (const float*)d_in[2], (const float*)d_in[3], (const float*)d_in[4],
      (const float*)d_in[5], (const float*)d_in[6], (const float*)d_in[7],
      wfc, pre, frag1, wfr, wfcq, gmax);

  dim3 gridc1(2, 128, 16);  // conv1: 2-row pairs
  conv1_mfma_kernel<<<gridc1, 256, 0, stream>>>(pre, frag1, A0);

  dim3 gf(86, 16);  // fused pairs: 3-row chunks (86*3 >= 256), full width
  conv_fused_kernel<0><<<gf, 512, 0, stream>>>(A0, wfr + 0 * 9216, wfr + 1 * 9216, A1, nullptr);
  conv_fused_kernel<0><<<gf, 512, 0, stream>>>(A1, wfr + 2 * 9216, wfr + 3 * 9216, A0, nullptr);
  conv_fused_kernel<1><<<gf, 512, 0, stream>>>(A0, wfr + 4 * 9216, wfr + 5 * 9216, nullptr, gmax);
  fc_kernel<<<1, 64, 0, stream>>>(gmax, wfcq, (float*)d_out);
}

// Round 18
// 160.489 us; speedup vs baseline: 1.9008x; 1.2680x over previous
//
#include <hip/hip_runtime.h>

#define BB 16
#define HH 256
#define WW 256

typedef int i32x4 __attribute__((ext_vector_type(4)));
typedef int i32x16 __attribute__((ext_vector_type(16)));
typedef float f32x16 __attribute__((ext_vector_type(16)));
typedef _Float16 f16x8 __attribute__((ext_vector_type(8)));

// ================= fused prep =================
__global__ __launch_bounds__(256) void prep_kernel(
    const float* __restrict__ x, const float* __restrict__ w1,
    const float* __restrict__ w2, const float* __restrict__ w3,
    const float* __restrict__ w4, const float* __restrict__ w5,
    const float* __restrict__ w6, const float* __restrict__ w7,
    const float* __restrict__ wfc,
    _Float16* __restrict__ pre, _Float16* __restrict__ frag1,
    signed char* __restrict__ wfr, int* __restrict__ wfcq,
    int* __restrict__ gmax) {
  int bid = blockIdx.x, tid = threadIdx.x;
  if (bid < 4096) {
    int px = bid * 256 + tid;  // 1,048,576 pixels
    int b = px >> 16, rem = px & 65535;
    const float* xp = x + (size_t)b * 4 * 65536 + rem;
    f16x8 o;
#pragma unroll
    for (int ic = 0; ic < 4; ++ic) {
      float v = xp[ic * 65536];
      _Float16 hf = (_Float16)v;
      float r = v - (float)hf;
      o[ic * 2] = hf;
      o[ic * 2 + 1] = (_Float16)r;
    }
    *(f16x8*)(pre + (size_t)px * 8) = o;
  } else if (bid < 4312) {
    int i = (bid - 4096) * 256 + tid;  // 6 x 9216
    int layer = i / 9216, within = i - layer * 9216;
    const float* w = layer == 0 ? w2 : layer == 1 ? w3 : layer == 2 ? w4
                   : layer == 3 ? w5 : layer == 4 ? w6 : w7;
    int t = within >> 10;
    int l = (within >> 4) & 63;
    int j = within & 15;
    int ic = (l >> 5) * 16 + j;
    int oc = l & 31;
    int q = (int)rintf(w[oc * 288 + ic * 9 + t] * 128.0f);
    q = min(127, max(-127, q));
    wfr[(size_t)layer * 9216 + within] = (signed char)q;
  } else {
    // conv1 f16 B-frags
    for (int p = tid; p < 384; p += 256) {
      int s = p >> 6, l = p & 63;
      int dr = s >> 1, pp = s & 1;
      int oc = l & 31, half = l >> 5;
      int dx = pp * 2 + half;
#pragma unroll
      for (int j = 0; j < 8; ++j) {
        int ic = j >> 1;
        _Float16 v = (_Float16)0.f;
        if (!(pp == 1 && half == 1)) {
          int q = (int)rintf(w1[oc * 36 + ic * 9 + dr * 3 + dx] * 128.0f);
          q = min(127, max(-127, q));
          v = (_Float16)((float)q * 0.0078125f);  // exact in fp16
        }
        frag1[s * 512 + l * 8 + j] = v;
      }
    }
    if (tid < 32) {
      int q = (int)rintf(wfc[tid] * 128.0f);
      q = min(127, max(-127, q));
      wfcq[tid] = q;
    }
    for (int i2 = tid; i2 < 512; i2 += 256) gmax[i2] = -128;
  }
}

__device__ __forceinline__ int pack4(int q0, int q1, int q2, int q3) {
  return (q0 & 255) | ((q1 & 255) << 8) | ((q2 & 255) << 16) | ((q3 & 255) << 24);
}

// Exact integer RNE: rne(a/128) = (a + 63 + ((a>>7)&1)) >> 7 (bit-identical
// to the verified rintf path), then clamp.
__device__ __forceinline__ int quant1(int a) {
  int q = (a + 63 + ((a >> 7) & 1)) >> 7;
  return min(127, max(-127, q));
}

__device__ __forceinline__ int quant_max(const i32x16& acc, int mymax) {
#pragma unroll
  for (int r = 0; r < 16; ++r) mymax = max(mymax, quant1(acc[r]));
  return mymax;
}

// Build this lane's contiguous 16B chunk from 4 packed dwords (d = 2g+hi)
// by exchanging two dwords with the partner lane (lane^32) via shfl.
// Result: hi=0 lane owns dwords d0..3 (oc 0..15), hi=1 lane d4..7 (oc 16..31).
__device__ __forceinline__ i32x4 half_swap(int v0, int v1, int v2, int v3, int hi) {
  int s0 = hi ? v0 : v2;
  int s1 = hi ? v1 : v3;
  int r0 = __shfl_xor(s0, 32);
  int r1 = __shfl_xor(s1, 32);
  i32x4 ch;
  ch.x = hi ? r0 : v0;
  ch.y = hi ? v2 : r0;
  ch.z = hi ? r1 : v1;
  ch.w = hi ? v3 : r1;
  return ch;
}

// ================= conv1: f16 hi/lo implicit-GEMM MFMA =================
// Swapped operands (A=weights) so lane owns pixel; epilogue = shfl-swap +
// one dwordx4 store per row (replaces 32 one-byte scatter stores).
__global__ __launch_bounds__(256) void conv1_mfma_kernel(
    const _Float16* __restrict__ pre, const _Float16* __restrict__ frag1,
    signed char* __restrict__ out) {
  int tid = threadIdx.x;
  int wi = tid >> 6;
  int l = tid & 63;
  int lo = l & 31;
  int hi = l >> 5;
  int b = blockIdx.z;
  int h0 = blockIdx.y * 2;
  int wbase = blockIdx.x * 128 + wi * 32;
  int w = wbase + lo;

  const f16x8* fp = (const f16x8*)frag1;
  f16x8 bf[6];
#pragma unroll
  for (int s = 0; s < 6; ++s) bf[s] = fp[s * 64 + l];

  f32x16 acc0 = {}, acc1 = {};
  const size_t img = (size_t)b * (HH * WW);

#pragma unroll
  for (int r = 0; r < 4; ++r) {  // input rows h0-1 .. h0+2
    int yy = h0 - 1 + r;
    bool okr = (unsigned)yy < 256u;
#pragma unroll
    for (int p = 0; p < 2; ++p) {
      int xx = w + p * 2 + hi - 1;  // dx = 2p + half
      f16x8 av = {};
      if (okr && !(p == 1 && hi == 1) && ((unsigned)xx < 256u))
        av = *(const f16x8*)(pre + ((img + (size_t)yy * WW + xx) << 3));
      if (r < 3) acc0 = __builtin_amdgcn_mfma_f32_32x32x16_f16(bf[r * 2 + p], av, acc0, 0, 0, 0);
      if (r > 0) acc1 = __builtin_amdgcn_mfma_f32_32x32x16_f16(bf[(r - 1) * 2 + p], av, acc1, 0, 0, 0);
    }
  }

  // lane owns px=w; oc = (r&3)+8*(r>>2)+4*hi -> dword d=2g+hi holds oc 4d..4d+3
#pragma unroll
  for (int rr = 0; rr < 2; ++rr) {
    const f32x16& acc = rr ? acc1 : acc0;
    int q[16];
#pragma unroll
    for (int r = 0; r < 16; ++r) {
      int t = (int)rintf(acc[r] * 128.0f);
      q[r] = min(127, max(-127, t));
    }
    int v0 = pack4(q[0], q[1], q[2], q[3]);
    int v1 = pack4(q[4], q[5], q[6], q[7]);
    int v2 = pack4(q[8], q[9], q[10], q[11]);
    int v3 = pack4(q[12], q[13], q[14], q[15]);
    i32x4 ch = half_swap(v0, v1, v2, v3, hi);
    *(i32x4*)(out + ((img + (size_t)(h0 + rr) * WW + w) << 5) + hi * 16) = ch;
  }
}

// ================= fused mid pairs (round-15 geometry) =================
// 4 layer-B rows per block, 6 A-rows in LDS. Phase-1 LDS writes and MODE-0
// global stores use half_swap + b128 (conflict-free streaming); this kills
// the 1.0-1.3e7 bank conflicts that scaled with phase-1 write count.
// MODE 0: layer B stores to global (lane owns px). MODE 1: per-oc max only.
template <int MODE>
__global__ __launch_bounds__(512, 4) void conv_fused_kernel(
    const signed char* __restrict__ in, const signed char* __restrict__ fragA,
    const signed char* __restrict__ fragB, signed char* __restrict__ out,
    int* __restrict__ gmax) {
  __shared__ int Lint[6 * 2 * 256 * 4];  // 49152 B, [rrel][half][px] 16B units
  __shared__ int lbf[2304];              // 9216 B, A-frags then B-frags
  __shared__ int red[8][32];

  int tid = threadIdx.x;
  int wi = tid >> 6;
  int l = tid & 63;
  int lo = l & 31;
  int hi = l >> 5;
  int b = blockIdx.y;
  int hs = blockIdx.x * 4;  // layer-B output rows hs..hs+3
  int w = wi * 32 + lo;     // this lane's pixel column
  const size_t img = (size_t)b * (HH * WW);

  const int* fA32 = (const int*)fragA;
  for (int i = tid; i < 2304; i += 512) lbf[i] = fA32[i];
  __syncthreads();

  auto ldrow = [&](int yy, int dx) -> i32x4 {
    i32x4 r = {};
    int xx = w + dx - 1;
    if (((unsigned)yy < 256u) && ((unsigned)xx < 256u))
      r = *(const i32x4*)(in + ((img + (size_t)yy * WW + xx) << 5) + hi * 16);
    return r;
  };

  auto lds_store_row = [&](const i32x16& acc, int rrel) {
    int v0 = pack4(quant1(acc[0]), quant1(acc[1]), quant1(acc[2]), quant1(acc[3]));
    int v1 = pack4(quant1(acc[4]), quant1(acc[5]), quant1(acc[6]), quant1(acc[7]));
    int v2 = pack4(quant1(acc[8]), quant1(acc[9]), quant1(acc[10]), quant1(acc[11]));
    int v3 = pack4(quant1(acc[12]), quant1(acc[13]), quant1(acc[14]), quant1(acc[15]));
    i32x4 ch = half_swap(v0, v1, v2, v3, hi);
    *(i32x4*)&Lint[((rrel * 2 + hi) * 256 + w) * 4] = ch;
  };

  // ---- phase 1: layer A rows hs-1..hs+4 (rrel 0..5), 3 pairs ----
#pragma unroll 1
  for (int p = 0; p < 3; ++p) {
    int ar0 = hs - 1 + 2 * p;  // first A-output row of this pair
    i32x4 rin[4][3];
#pragma unroll
    for (int rr = 0; rr < 4; ++rr)
#pragma unroll
      for (int dx = 0; dx < 3; ++dx)
        rin[rr][dx] = ldrow(ar0 - 1 + rr, dx);

    int pz = 0;
    asm volatile("" : "+v"(pz));  // force per-pair LDS weight re-read
    i32x16 acc0 = {}, acc1 = {};
#pragma unroll
    for (int t = 0; t < 9; ++t) {
      int dy = t / 3, dx = t % 3;
      i32x4 bfv = *(const i32x4*)&lbf[(t * 64 + l) * 4 + pz];
      acc0 = __builtin_amdgcn_mfma_i32_32x32x32_i8(bfv, rin[dy][dx], acc0, 0, 0, 0);
      acc1 = __builtin_amdgcn_mfma_i32_32x32x32_i8(bfv, rin[dy + 1][dx], acc1, 0, 0, 0);
    }
    lds_store_row(acc0, 2 * p);
    lds_store_row(acc1, 2 * p + 1);
  }

  __syncthreads();
  const int* fB32 = (const int*)fragB;
  for (int i = tid; i < 2304; i += 512) lbf[i] = fB32[i];
  __syncthreads();

  // ---- phase 2: layer B rows hs..hs+3 from LDS, 2 pairs ----
  int mymax = -128;
#pragma unroll 1
  for (int p = 0; p < 2; ++p) {
    i32x4 tp[4][3];
#pragma unroll
    for (int rr = 0; rr < 4; ++rr) {
      int rrel = 2 * p + rr;
      int aro = hs - 1 + rrel;  // absolute layer-A row
#pragma unroll
      for (int dx = 0; dx < 3; ++dx) {
        int px = w + dx - 1;
        i32x4 v = {};
        if (((unsigned)aro < 256u) && ((unsigned)px < 256u))
          v = *(const i32x4*)&Lint[((rrel * 2 + hi) * 256 + px) * 4];
        tp[rr][dx] = v;
      }
    }
    int pz = 0;
    asm volatile("" : "+v"(pz));
    i32x16 acc0 = {}, acc1 = {};
#pragma unroll
    for (int t = 0; t < 9; ++t) {
      int dy = t / 3, dx = t % 3;
      i32x4 bfv = *(const i32x4*)&lbf[(t * 64 + l) * 4 + pz];
      if (MODE == 1) {
        acc0 = __builtin_amdgcn_mfma_i32_32x32x32_i8(tp[dy][dx], bfv, acc0, 0, 0, 0);
        acc1 = __builtin_amdgcn_mfma_i32_32x32x32_i8(tp[dy + 1][dx], bfv, acc1, 0, 0, 0);
      } else {
        acc0 = __builtin_amdgcn_mfma_i32_32x32x32_i8(bfv, tp[dy][dx], acc0, 0, 0, 0);
        acc1 = __builtin_amdgcn_mfma_i32_32x32x32_i8(bfv, tp[dy + 1][dx], acc1, 0, 0, 0);
      }
    }
    if (MODE == 0) {
#pragma unroll
      for (int rr = 0; rr < 2; ++rr) {
        const i32x16& acc = rr ? acc1 : acc0;
        int v0 = pack4(quant1(acc[0]), quant1(acc[1]), quant1(acc[2]), quant1(acc[3]));
        int v1 = pack4(quant1(acc[4]), quant1(acc[5]), quant1(acc[6]), quant1(acc[7]));
        int v2 = pack4(quant1(acc[8]), quant1(acc[9]), quant1(acc[10]), quant1(acc[11]));
        int v3 = pack4(quant1(acc[12]), quant1(acc[13]), quant1(acc[14]), quant1(acc[15]));
        i32x4 ch = half_swap(v0, v1, v2, v3, hi);
        *(i32x4*)(out + ((img + (size_t)(hs + 2 * p + rr) * WW + w) << 5) + hi * 16) = ch;
      }
    } else {
      mymax = quant_max(acc1, quant_max(acc0, mymax));
    }
  }

  if (MODE == 1) {
    mymax = max(mymax, __shfl_xor(mymax, 32));  // lanes lo & lo+32: same oc
    if (hi == 0) red[wi][lo] = mymax;
    __syncthreads();
    if (tid < 32) {
      int m = -128;
#pragma unroll
      for (int r = 0; r < 8; ++r) m = max(m, red[r][tid]);
      atomicMax(&gmax[b * 32 + tid], m);
    }
  }
}

// ================= final FC =================
__global__ void fc_kernel(const int* __restrict__ gmax, const int* __restrict__ wfcq,
                          float* __restrict__ out) {
  int b = threadIdx.x;
  if (b < BB) {
    int acc = 0;
#pragma unroll
    for (int c = 0; c < 32; ++c) acc += gmax[b * 32 + c] * wfcq[c];
    int q = (acc + 63 + ((acc >> 7) & 1)) >> 7;  // rne(acc/128), exact
    q = min(127, max(-127, q));
    out[b] = (float)q * 0.0078125f;
  }
}

extern "C" void kernel_launch(void* const* d_in, const int* in_sizes, int n_in,
                              void* d_out, int out_size, void* d_ws, size_t ws_size,
                              hipStream_t stream) {
  const float* x   = (const float*)d_in[0];
  const float* w1  = (const float*)d_in[1];
  const float* wfc = (const float*)d_in[8];

  char* ws = (char*)d_ws;
  const size_t ACTB = (size_t)BB * HH * WW * 32;  // 33,554,432 B
  signed char* A0    = (signed char*)ws;
  signed char* A1    = (signed char*)(ws + ACTB);
  _Float16*    pre   = (_Float16*)A1;  // dead before F0 writes A1
  _Float16*    frag1 = (_Float16*)(ws + 2 * ACTB);                 // 6144 B
  signed char* wfr   = (signed char*)(ws + 2 * ACTB + 6144);       // 6 x 9216
  int*         wfcq  = (int*)(ws + 2 * ACTB + 6144 + 6 * 9216);
  int*         gmax  = (int*)(ws + 2 * ACTB + 6144 + 6 * 9216 + 128);

  prep_kernel<<<4313, 256, 0, stream>>>(
      x, w1, (const float*)d_in[2], (const float*)d_in[3], (const float*)d_in[4],
      (const float*)d_in[5], (const float*)d_in[6], (const float*)d_in[7],
      wfc, pre, frag1, wfr, wfcq, gmax);

  dim3 gridc1(2, 128, 16);  // conv1: 2-row pairs
  conv1_mfma_kernel<<<gridc1, 256, 0, stream>>>(pre, frag1, A0);

  dim3 gf(64, 16);  // fused pairs: 4-row chunks, full width
  conv_fused_kernel<0><<<gf, 512, 0, stream>>>(A0, wfr + 0 * 9216, wfr + 1 * 9216, A1, nullptr);
  conv_fused_kernel<0><<<gf, 512, 0, stream>>>(A1, wfr + 2 * 9216, wfr + 3 * 9216, A0, nullptr);
  conv_fused_kernel<1><<<gf, 512, 0, stream>>>(A0, wfr + 4 * 9216, wfr + 5 * 9216, nullptr, gmax);
  fc_kernel<<<1, 64, 0, stream>>>(gmax, wfcq, (float*)d_out);
}

// Round 20
// 138.496 us; speedup vs baseline: 2.2026x; 1.1588x over previous
//
#include <hip/hip_runtime.h>

#define BB 16
#define HH 256
#define WW 256

typedef int i32x4 __attribute__((ext_vector_type(4)));
typedef int i32x16 __attribute__((ext_vector_type(16)));
typedef float f32x16 __attribute__((ext_vector_type(16)));
typedef _Float16 f16x8 __attribute__((ext_vector_type(8)));

// ================= fused prep =================
__global__ __launch_bounds__(256) void prep_kernel(
    const float* __restrict__ x, const float* __restrict__ w1,
    const float* __restrict__ w2, const float* __restrict__ w3,
    const float* __restrict__ w4, const float* __restrict__ w5,
    const float* __restrict__ w6, const float* __restrict__ w7,
    const float* __restrict__ wfc,
    _Float16* __restrict__ pre, _Float16* __restrict__ frag1,
    signed char* __restrict__ wfr, int* __restrict__ wfcq,
    int* __restrict__ gmax) {
  int bid = blockIdx.x, tid = threadIdx.x;
  if (bid < 4096) {
    int px = bid * 256 + tid;  // 1,048,576 pixels
    int b = px >> 16, rem = px & 65535;
    const float* xp = x + (size_t)b * 4 * 65536 + rem;
    f16x8 o;
#pragma unroll
    for (int ic = 0; ic < 4; ++ic) {
      float v = xp[ic * 65536];
      _Float16 hf = (_Float16)v;
      float r = v - (float)hf;
      o[ic * 2] = hf;
      o[ic * 2 + 1] = (_Float16)r;
    }
    *(f16x8*)(pre + (size_t)px * 8) = o;
  } else if (bid < 4312) {
    int i = (bid - 4096) * 256 + tid;  // 6 x 9216
    int layer = i / 9216, within = i - layer * 9216;
    const float* w = layer == 0 ? w2 : layer == 1 ? w3 : layer == 2 ? w4
                   : layer == 3 ? w5 : layer == 4 ? w6 : w7;
    int t = within >> 10;
    int l = (within >> 4) & 63;
    int j = within & 15;
    int ic = (l >> 5) * 16 + j;
    int oc = l & 31;
    int q = (int)rintf(w[oc * 288 + ic * 9 + t] * 128.0f);
    q = min(127, max(-127, q));
    wfr[(size_t)layer * 9216 + within] = (signed char)q;
  } else {
    // conv1 f16 B-frags
    for (int p = tid; p < 384; p += 256) {
      int s = p >> 6, l = p & 63;
      int dr = s >> 1, pp = s & 1;
      int oc = l & 31, half = l >> 5;
      int dx = pp * 2 + half;
#pragma unroll
      for (int j = 0; j < 8; ++j) {
        int ic = j >> 1;
        _Float16 v = (_Float16)0.f;
        if (!(pp == 1 && half == 1)) {
          int q = (int)rintf(w1[oc * 36 + ic * 9 + dr * 3 + dx] * 128.0f);
          q = min(127, max(-127, q));
          v = (_Float16)((float)q * 0.0078125f);  // exact in fp16
        }
        frag1[s * 512 + l * 8 + j] = v;
      }
    }
    if (tid < 32) {
      int q = (int)rintf(wfc[tid] * 128.0f);
      q = min(127, max(-127, q));
      wfcq[tid] = q;
    }
    for (int i2 = tid; i2 < 512; i2 += 256) gmax[i2] = -128;
  }
}

__device__ __forceinline__ int pack4(int q0, int q1, int q2, int q3) {
  return (q0 & 255) | ((q1 & 255) << 8) | ((q2 & 255) << 16) | ((q3 & 255) << 24);
}

// Exact integer RNE: rne(a/128) = (a + 63 + ((a>>7)&1)) >> 7 (bit-identical
// to the verified rintf path), then clamp.
__device__ __forceinline__ int quant1(int a) {
  int q = (a + 63 + ((a >> 7) & 1)) >> 7;
  return min(127, max(-127, q));
}

__device__ __forceinline__ int quant_max(const i32x16& acc, int mymax) {
#pragma unroll
  for (int r = 0; r < 16; ++r) mymax = max(mymax, quant1(acc[r]));
  return mymax;
}

// Build this lane's contiguous 16B chunk from 4 packed dwords (d = 2g+hi)
// by exchanging two dwords with the partner lane (lane^32) via shfl.
__device__ __forceinline__ i32x4 half_swap(int v0, int v1, int v2, int v3, int hi) {
  int s0 = hi ? v0 : v2;
  int s1 = hi ? v1 : v3;
  int r0 = __shfl_xor(s0, 32);
  int r1 = __shfl_xor(s1, 32);
  i32x4 ch;
  ch.x = hi ? r0 : v0;
  ch.y = hi ? v2 : r0;
  ch.z = hi ? r1 : v1;
  ch.w = hi ? v3 : r1;
  return ch;
}

// ================= conv1: f16 hi/lo implicit-GEMM MFMA =================
__global__ __launch_bounds__(256) void conv1_mfma_kernel(
    const _Float16* __restrict__ pre, const _Float16* __restrict__ frag1,
    signed char* __restrict__ out) {
  int tid = threadIdx.x;
  int wi = tid >> 6;
  int l = tid & 63;
  int lo = l & 31;
  int hi = l >> 5;
  int b = blockIdx.z;
  int h0 = blockIdx.y * 2;
  int wbase = blockIdx.x * 128 + wi * 32;
  int w = wbase + lo;

  const f16x8* fp = (const f16x8*)frag1;
  f16x8 bf[6];
#pragma unroll
  for (int s = 0; s < 6; ++s) bf[s] = fp[s * 64 + l];

  f32x16 acc0 = {}, acc1 = {};
  const size_t img = (size_t)b * (HH * WW);

#pragma unroll
  for (int r = 0; r < 4; ++r) {  // input rows h0-1 .. h0+2
    int yy = h0 - 1 + r;
    bool okr = (unsigned)yy < 256u;
#pragma unroll
    for (int p = 0; p < 2; ++p) {
      int xx = w + p * 2 + hi - 1;  // dx = 2p + half
      f16x8 av = {};
      if (okr && !(p == 1 && hi == 1) && ((unsigned)xx < 256u))
        av = *(const f16x8*)(pre + ((img + (size_t)yy * WW + xx) << 3));
      if (r < 3) acc0 = __builtin_amdgcn_mfma_f32_32x32x16_f16(bf[r * 2 + p], av, acc0, 0, 0, 0);
      if (r > 0) acc1 = __builtin_amdgcn_mfma_f32_32x32x16_f16(bf[(r - 1) * 2 + p], av, acc1, 0, 0, 0);
    }
  }

  // lane owns px=w; oc = (r&3)+8*(r>>2)+4*hi -> dword d=2g+hi holds oc 4d..4d+3
#pragma unroll
  for (int rr = 0; rr < 2; ++rr) {
    const f32x16& acc = rr ? acc1 : acc0;
    int q[16];
#pragma unroll
    for (int r = 0; r < 16; ++r) {
      int t = (int)rintf(acc[r] * 128.0f);
      q[r] = min(127, max(-127, t));
    }
    int v0 = pack4(q[0], q[1], q[2], q[3]);
    int v1 = pack4(q[4], q[5], q[6], q[7]);
    int v2 = pack4(q[8], q[9], q[10], q[11]);
    int v3 = pack4(q[12], q[13], q[14], q[15]);
    i32x4 ch = half_swap(v0, v1, v2, v3, hi);
    *(i32x4*)(out + ((img + (size_t)(h0 + rr) * WW + w) << 5) + hi * 16) = ch;
  }
}

// ================= fused mid pairs =================
// 4 layer-B rows per block, 6 A-rows in LDS. Weight fragments live in 36
// VGPRs loaded from GLOBAL (L2-hot broadcast) — no LDS weight reads at all
// (they were the persistent ~9e6 bank-conflict source: ~45 reads/thread of
// 16B chunks from one 1KB region). LDS now holds only the intermediate tile.
// MODE 0: layer B stores to global (lane owns px). MODE 1: per-oc max only.
template <int MODE>
__global__ __launch_bounds__(512, 4) void conv_fused_kernel(
    const signed char* __restrict__ in, const signed char* __restrict__ fragA,
    const signed char* __restrict__ fragB, signed char* __restrict__ out,
    int* __restrict__ gmax) {
  __shared__ int Lint[6 * 2 * 256 * 4];  // 49152 B, [rrel][half][px] 16B units
  __shared__ int red[8][32];             // 1024 B (MODE 1)

  int tid = threadIdx.x;
  int wi = tid >> 6;
  int l = tid & 63;
  int lo = l & 31;
  int hi = l >> 5;
  int b = blockIdx.y;
  int hs = blockIdx.x * 4;  // layer-B output rows hs..hs+3
  int w = wi * 32 + lo;     // this lane's pixel column
  const size_t img = (size_t)b * (HH * WW);

  const i32x4* fpA = (const i32x4*)fragA;
  i32x4 bw[9];
#pragma unroll
  for (int t = 0; t < 9; ++t) bw[t] = fpA[t * 64 + l];

  auto ldrow = [&](int yy, int dx) -> i32x4 {
    i32x4 r = {};
    int xx = w + dx - 1;
    if (((unsigned)yy < 256u) && ((unsigned)xx < 256u))
      r = *(const i32x4*)(in + ((img + (size_t)yy * WW + xx) << 5) + hi * 16);
    return r;
  };

  auto lds_store_row = [&](const i32x16& acc, int rrel) {
    int v0 = pack4(quant1(acc[0]), quant1(acc[1]), quant1(acc[2]), quant1(acc[3]));
    int v1 = pack4(quant1(acc[4]), quant1(acc[5]), quant1(acc[6]), quant1(acc[7]));
    int v2 = pack4(quant1(acc[8]), quant1(acc[9]), quant1(acc[10]), quant1(acc[11]));
    int v3 = pack4(quant1(acc[12]), quant1(acc[13]), quant1(acc[14]), quant1(acc[15]));
    i32x4 ch = half_swap(v0, v1, v2, v3, hi);
    *(i32x4*)&Lint[((rrel * 2 + hi) * 256 + w) * 4] = ch;
  };

  // ---- phase 1: layer A rows hs-1..hs+4 (rrel 0..5), 3 pairs ----
#pragma unroll 1
  for (int p = 0; p < 3; ++p) {
    int ar0 = hs - 1 + 2 * p;  // first A-output row of this pair
    i32x4 rin[4][3];
#pragma unroll
    for (int rr = 0; rr < 4; ++rr)
#pragma unroll
      for (int dx = 0; dx < 3; ++dx)
        rin[rr][dx] = ldrow(ar0 - 1 + rr, dx);

    i32x16 acc0 = {}, acc1 = {};
#pragma unroll
    for (int t = 0; t < 9; ++t) {
      int dy = t / 3, dx = t % 3;
      acc0 = __builtin_amdgcn_mfma_i32_32x32x32_i8(bw[t], rin[dy][dx], acc0, 0, 0, 0);
      acc1 = __builtin_amdgcn_mfma_i32_32x32x32_i8(bw[t], rin[dy + 1][dx], acc1, 0, 0, 0);
    }
    lds_store_row(acc0, 2 * p);
    lds_store_row(acc1, 2 * p + 1);
  }

  // reload weight regs with B-frags (global, L2-hot) before the barrier
  const i32x4* fpB = (const i32x4*)fragB;
#pragma unroll
  for (int t = 0; t < 9; ++t) bw[t] = fpB[t * 64 + l];
  __syncthreads();

  // ---- phase 2: layer B rows hs..hs+3 from LDS, 2 pairs ----
  int mymax = -128;
#pragma unroll 1
  for (int p = 0; p < 2; ++p) {
    i32x4 tp[4][3];
#pragma unroll
    for (int rr = 0; rr < 4; ++rr) {
      int rrel = 2 * p + rr;
      int aro = hs - 1 + rrel;  // absolute layer-A row
#pragma unroll
      for (int dx = 0; dx < 3; ++dx) {
        int px = w + dx - 1;
        i32x4 v = {};
        if (((unsigned)aro < 256u) && ((unsigned)px < 256u))
          v = *(const i32x4*)&Lint[((rrel * 2 + hi) * 256 + px) * 4];
        tp[rr][dx] = v;
      }
    }
    i32x16 acc0 = {}, acc1 = {};
#pragma unroll
    for (int t = 0; t < 9; ++t) {
      int dy = t / 3, dx = t % 3;
      if (MODE == 1) {
        acc0 = __builtin_amdgcn_mfma_i32_32x32x32_i8(tp[dy][dx], bw[t], acc0, 0, 0, 0);
        acc1 = __builtin_amdgcn_mfma_i32_32x32x32_i8(tp[dy + 1][dx], bw[t], acc1, 0, 0, 0);
      } else {
        acc0 = __builtin_amdgcn_mfma_i32_32x32x32_i8(bw[t], tp[dy][dx], acc0, 0, 0, 0);
        acc1 = __builtin_amdgcn_mfma_i32_32x32x32_i8(bw[t], tp[dy + 1][dx], acc1, 0, 0, 0);
      }
    }
    if (MODE == 0) {
#pragma unroll
      for (int rr = 0; rr < 2; ++rr) {
        const i32x16& acc = rr ? acc1 : acc0;
        int v0 = pack4(quant1(acc[0]), quant1(acc[1]), quant1(acc[2]), quant1(acc[3]));
        int v1 = pack4(quant1(acc[4]), quant1(acc[5]), quant1(acc[6]), quant1(acc[7]));
        int v2 = pack4(quant1(acc[8]), quant1(acc[9]), quant1(acc[10]), quant1(acc[11]));
        int v3 = pack4(quant1(acc[12]), quant1(acc[13]), quant1(acc[14]), quant1(acc[15]));
        i32x4 ch = half_swap(v0, v1, v2, v3, hi);
        *(i32x4*)(out + ((img + (size_t)(hs + 2 * p + rr) * WW + w) << 5) + hi * 16) = ch;
      }
    } else {
      mymax = quant_max(acc1, quant_max(acc0, mymax));
    }
  }

  if (MODE == 1) {
    mymax = max(mymax, __shfl_xor(mymax, 32));  // lanes lo & lo+32: same oc
    if (hi == 0) red[wi][lo] = mymax;
    __syncthreads();
    if (tid < 32) {
      int m = -128;
#pragma unroll
      for (int r = 0; r < 8; ++r) m = max(m, red[r][tid]);
      atomicMax(&gmax[b * 32 + tid], m);
    }
  }
}

// ================= final FC =================
__global__ void fc_kernel(const int* __restrict__ gmax, const int* __restrict__ wfcq,
                          float* __restrict__ out) {
  int b = threadIdx.x;
  if (b < BB) {
    int acc = 0;
#pragma unroll
    for (int c = 0; c < 32; ++c) acc += gmax[b * 32 + c] * wfcq[c];
    int q = (acc + 63 + ((acc >> 7) & 1)) >> 7;  // rne(acc/128), exact
    q = min(127, max(-127, q));
    out[b] = (float)q * 0.0078125f;
  }
}

extern "C" void kernel_launch(void* const* d_in, const int* in_sizes, int n_in,
                              void* d_out, int out_size, void* d_ws, size_t ws_size,
                              hipStream_t stream) {
  const float* x   = (const float*)d_in[0];
  const float* w1  = (const float*)d_in[1];
  const float* wfc = (const float*)d_in[8];

  char* ws = (char*)d_ws;
  const size_t ACTB = (size_t)BB * HH * WW * 32;  // 33,554,432 B
  signed char* A0    = (signed char*)ws;
  signed char* A1    = (signed char*)(ws + ACTB);
  _Float16*    pre   = (_Float16*)A1;  // dead before F0 writes A1
  _Float16*    frag1 = (_Float16*)(ws + 2 * ACTB);                 // 6144 B
  signed char* wfr   = (signed char*)(ws + 2 * ACTB + 6144);       // 6 x 9216
  int*         wfcq  = (int*)(ws + 2 * ACTB + 6144 + 6 * 9216);
  int*         gmax  = (int*)(ws + 2 * ACTB + 6144 + 6 * 9216 + 128);

  prep_kernel<<<4313, 256, 0, stream>>>(
      x, w1, (const float*)d_in[2], (const float*)d_in[3], (const float*)d_in[4],
      (const float*)d_in[5], (const float*)d_in[6], (const float*)d_in[7],
      wfc, pre, frag1, wfr, wfcq, gmax);

  dim3 gridc1(2, 128, 16);  // conv1: 2-row pairs
  conv1_mfma_kernel<<<gridc1, 256, 0, stream>>>(pre, frag1, A0);

  dim3 gf(64, 16);  // fused pairs: 4-row chunks, full width
  conv_fused_kernel<0><<<gf, 512, 0, stream>>>(A0, wfr + 0 * 9216, wfr + 1 * 9216, A1, nullptr);
  conv_fused_kernel<0><<<gf, 512, 0, stream>>>(A1, wfr + 2 * 9216, wfr + 3 * 9216, A0, nullptr);
  conv_fused_kernel<1><<<gf, 512, 0, stream>>>(A0, wfr + 4 * 9216, wfr + 5 * 9216, nullptr, gmax);
  fc_kernel<<<1, 64, 0, stream>>>(gmax, wfcq, (float*)d_out);
}

// Round 24
// 136.193 us; speedup vs baseline: 2.2399x; 1.0169x over previous
//
#include <hip/hip_runtime.h>

#define BB 16
#define HH 256
#define WW 256
#define PC 258                 // padded cols/rows
#define PP ((size_t)(PC * PC)) // 66564 px per padded img

typedef int i32x4 __attribute__((ext_vector_type(4)));
typedef int i32x16 __attribute__((ext_vector_type(16)));
typedef float f32x16 __attribute__((ext_vector_type(16)));
typedef _Float16 f16x8 __attribute__((ext_vector_type(8)));

// ================= fused prep =================
// [0,4096): x NCHW -> padded pre (f16 hi/lo pairs). [4096,4312): mid weight
// frags. 4312: conv1 frags + wfc + gmax. [4313,4378): zero pads of pre & A0.
__global__ __launch_bounds__(256) void prep_kernel(
    const float* __restrict__ x, const float* __restrict__ w1,
    const float* __restrict__ w2, const float* __restrict__ w3,
    const float* __restrict__ w4, const float* __restrict__ w5,
    const float* __restrict__ w6, const float* __restrict__ w7,
    const float* __restrict__ wfc,
    _Float16* __restrict__ pre, _Float16* __restrict__ frag1,
    signed char* __restrict__ wfr, int* __restrict__ wfcq,
    int* __restrict__ gmax, signed char* __restrict__ A0) {
  int bid = blockIdx.x, tid = threadIdx.x;
  if (bid < 4096) {
    int px = bid * 256 + tid;  // 1,048,576 interior pixels
    int b = px >> 16, rem = px & 65535;
    int y = rem >> 8, xc = rem & 255;
    const float* xp = x + (size_t)b * 4 * 65536 + rem;
    f16x8 o;
#pragma unroll
    for (int ic = 0; ic < 4; ++ic) {
      float v = xp[ic * 65536];
      _Float16 hf = (_Float16)v;
      float r = v - (float)hf;
      o[ic * 2] = hf;
      o[ic * 2 + 1] = (_Float16)r;
    }
    *(f16x8*)(pre + ((size_t)b * PP + (size_t)(y + 1) * PC + (xc + 1)) * 8) = o;
  } else if (bid < 4312) {
    int i = (bid - 4096) * 256 + tid;  // 6 x 9216
    int layer = i / 9216, within = i - layer * 9216;
    const float* w = layer == 0 ? w2 : layer == 1 ? w3 : layer == 2 ? w4
                   : layer == 3 ? w5 : layer == 4 ? w6 : w7;
    int t = within >> 10;
    int l = (within >> 4) & 63;
    int j = within & 15;
    int ic = (l >> 5) * 16 + j;
    int oc = l & 31;
    int q = (int)rintf(w[oc * 288 + ic * 9 + t] * 128.0f);
    q = min(127, max(-127, q));
    wfr[(size_t)layer * 9216 + within] = (signed char)q;
  } else if (bid == 4312) {
    for (int p = tid; p < 384; p += 256) {
      int s = p >> 6, l = p & 63;
      int dr = s >> 1, pp = s & 1;
      int oc = l & 31, half = l >> 5;
      int dx = pp * 2 + half;
#pragma unroll
      for (int j = 0; j < 8; ++j) {
        int ic = j >> 1;
        _Float16 v = (_Float16)0.f;
        if (!(pp == 1 && half == 1)) {
          int q = (int)rintf(w1[oc * 36 + ic * 9 + dr * 3 + dx] * 128.0f);
          q = min(127, max(-127, q));
          v = (_Float16)((float)q * 0.0078125f);  // exact in fp16
        }
        frag1[s * 512 + l * 8 + j] = v;
      }
    }
    if (tid < 32) {
      int q = (int)rintf(wfc[tid] * 128.0f);
      q = min(127, max(-127, q));
      wfcq[tid] = q;
    }
    for (int i2 = tid; i2 < 512; i2 += 256) gmax[i2] = -128;
  } else {
    int idx = (bid - 4313) * 256 + tid;  // 16*1028 = 16448 pad px
    if (idx < 16448) {
      int img = idx / 1028, p = idx - img * 1028;
      int row, col;
      if (p < 258) { row = 0; col = p; }
      else if (p < 516) { row = 257; col = p - 258; }
      else { int q2 = p - 516; row = 1 + (q2 & 255); col = (q2 >> 8) ? 257 : 0; }
      size_t off = (size_t)img * PP + (size_t)row * PC + col;
      f16x8 z16 = {};
      *(f16x8*)(pre + off * 8) = z16;
      i32x4 z = {};
      ((i32x4*)(A0 + off * 32))[0] = z;
      ((i32x4*)(A0 + off * 32 + 16))[0] = z;
    }
  }
}

// zero the pads of A1 (must run AFTER conv1 consumed pre, which aliases A1)
__global__ __launch_bounds__(256) void pad_kernel(signed char* __restrict__ A1) {
  int idx = blockIdx.x * 256 + threadIdx.x;
  if (idx < 16448) {
    int img = idx / 1028, p = idx - img * 1028;
    int row, col;
    if (p < 258) { row = 0; col = p; }
    else if (p < 516) { row = 257; col = p - 258; }
    else { int q2 = p - 516; row = 1 + (q2 & 255); col = (q2 >> 8) ? 257 : 0; }
    size_t off = (size_t)img * PP + (size_t)row * PC + col;
    i32x4 z = {};
    ((i32x4*)(A1 + off * 32))[0] = z;
    ((i32x4*)(A1 + off * 32 + 16))[0] = z;
  }
}

__device__ __forceinline__ int pack4(int q0, int q1, int q2, int q3) {
  return (q0 & 255) | ((q1 & 255) << 8) | ((q2 & 255) << 16) | ((q3 & 255) << 24);
}

// Exact integer RNE: rne(a/128) = (a + 63 + ((a>>7)&1)) >> 7, bit-identical.
__device__ __forceinline__ int quant1(int a) {
  int q = (a + 63 + ((a >> 7) & 1)) >> 7;
  return min(127, max(-127, q));
}

__device__ __forceinline__ int quant_max(const i32x16& acc, int mymax) {
#pragma unroll
  for (int r = 0; r < 16; ++r) mymax = max(mymax, quant1(acc[r]));
  return mymax;
}

__device__ __forceinline__ i32x4 half_swap(int v0, int v1, int v2, int v3, int hi) {
  int s0 = hi ? v0 : v2;
  int s1 = hi ? v1 : v3;
  int r0 = __shfl_xor(s0, 32);
  int r1 = __shfl_xor(s1, 32);
  i32x4 ch;
  ch.x = hi ? r0 : v0;
  ch.y = hi ? v2 : r0;
  ch.z = hi ? r1 : v1;
  ch.w = hi ? v3 : r1;
  return ch;
}

// ================= conv1: padded pre -> padded A0, no bounds checks ======
__global__ __launch_bounds__(256) void conv1_mfma_kernel(
    const _Float16* __restrict__ pre, const _Float16* __restrict__ frag1,
    signed char* __restrict__ out) {
  int tid = threadIdx.x;
  int wi = tid >> 6;
  int l = tid & 63;
  int lo = l & 31;
  int hi = l >> 5;
  int b = blockIdx.z;
  int h0 = blockIdx.y * 2;
  int wbase = blockIdx.x * 128 + wi * 32;
  int w = wbase + lo;

  const f16x8* fp = (const f16x8*)frag1;
  f16x8 bf[6];
#pragma unroll
  for (int s = 0; s < 6; ++s) bf[s] = fp[s * 64 + l];

  f32x16 acc0 = {}, acc1 = {};

#pragma unroll
  for (int r = 0; r < 4; ++r) {  // input rows h0-1 .. h0+2 -> padded h0+r
    const _Float16* rp = pre + ((size_t)b * PP + (size_t)(h0 + r) * PC) * 8;
#pragma unroll
    for (int p = 0; p < 2; ++p) {
      int col = w + p * 2 + hi;  // padded col of x = w+2p+hi-1
      f16x8 av = {};
      if (!(p == 1 && hi == 1))  // k-slot pad only (not spatial)
        av = *(const f16x8*)(rp + (size_t)col * 8);
      if (r < 3) acc0 = __builtin_amdgcn_mfma_f32_32x32x16_f16(bf[r * 2 + p], av, acc0, 0, 0, 0);
      if (r > 0) acc1 = __builtin_amdgcn_mfma_f32_32x32x16_f16(bf[(r - 1) * 2 + p], av, acc1, 0, 0, 0);
    }
  }

#pragma unroll
  for (int rr = 0; rr < 2; ++rr) {
    const f32x16& acc = rr ? acc1 : acc0;
    int q[16];
#pragma unroll
    for (int r = 0; r < 16; ++r) {
      int t = (int)rintf(acc[r] * 128.0f);
      q[r] = min(127, max(-127, t));
    }
    int v0 = pack4(q[0], q[1], q[2], q[3]);
    int v1 = pack4(q[4], q[5], q[6], q[7]);
    int v2 = pack4(q[8], q[9], q[10], q[11]);
    int v3 = pack4(q[12], q[13], q[14], q[15]);
    i32x4 ch = half_swap(v0, v1, v2, v3, hi);
    *(i32x4*)(out + ((size_t)b * PP + (size_t)(h0 + rr + 1) * PC + (w + 1)) * 32 + hi * 16) = ch;
  }
}

// ================= fused mid pairs, padded I/O =================
// Weights in 36 VGPRs from global; LDS tile [6 rrel][2 half][258 col] 16B
// units with zeroed col halo; no spatial bounds checks anywhere.
template <int MODE>
__global__ __launch_bounds__(512, 4) void conv_fused_kernel(
    const signed char* __restrict__ in, const signed char* __restrict__ fragA,
    const signed char* __restrict__ fragB, signed char* __restrict__ out,
    int* __restrict__ gmax) {
  __shared__ int Lint[6 * 2 * PC * 4];  // 49536 B
  __shared__ int red[8][32];

  int tid = threadIdx.x;
  int wi = tid >> 6;
  int l = tid & 63;
  int lo = l & 31;
  int hi = l >> 5;
  int b = blockIdx.y;
  int hs = blockIdx.x * 4;  // layer-B output rows hs..hs+3
  int w = wi * 32 + lo;

  // zero LDS col halo (cols 0 and 257 of each of 12 subrows)
  if (tid < 24) {
    int rr = tid >> 2, half = (tid >> 1) & 1, cs = tid & 1;
    i32x4 z = {};
    *(i32x4*)&Lint[((rr * 2 + half) * PC + (cs ? 257 : 0)) * 4] = z;
  }

  const i32x4* fpA = (const i32x4*)fragA;
  i32x4 bw[9];
#pragma unroll
  for (int t = 0; t < 9; ++t) bw[t] = fpA[t * 64 + l];

  int lanep = (w << 5) + (hi << 4);  // lane part of padded addr (col=w base)

  auto rowptr = [&](int yy) -> const signed char* {  // input row yy, col w+dx via imm
    int prow = min(max(yy + 1, 0), 257);  // clamp: garbage rows get discarded
    return in + ((size_t)b * PP + (size_t)prow * PC) * 32 + lanep;
  };

  auto lds_store_row = [&](const i32x16& acc, int rrel, bool valid) {
    int v0 = pack4(quant1(acc[0]), quant1(acc[1]), quant1(acc[2]), quant1(acc[3]));
    int v1 = pack4(quant1(acc[4]), quant1(acc[5]), quant1(acc[6]), quant1(acc[7]));
    int v2 = pack4(quant1(acc[8]), quant1(acc[9]), quant1(acc[10]), quant1(acc[11]));
    int v3 = pack4(quant1(acc[12]), quant1(acc[13]), quant1(acc[14]), quant1(acc[15]));
    i32x4 ch = half_swap(v0, v1, v2, v3, hi);
    if (!valid) ch = i32x4{};
    *(i32x4*)&Lint[((rrel * 2 + hi) * PC + (w + 1)) * 4] = ch;
  };

  // ---- phase 1: layer A rows hs-1..hs+4 (rrel 0..5), 3 pairs ----
#pragma unroll 1
  for (int p = 0; p < 3; ++p) {
    int ar0 = hs - 1 + 2 * p;
    const signed char* rp[4];
#pragma unroll
    for (int rr = 0; rr < 4; ++rr) rp[rr] = rowptr(ar0 - 1 + rr);
    i32x4 rin[4][3];
#pragma unroll
    for (int rr = 0; rr < 4; ++rr)
#pragma unroll
      for (int dx = 0; dx < 3; ++dx)
        rin[rr][dx] = *(const i32x4*)(rp[rr] + dx * 32);

    i32x16 acc0 = {}, acc1 = {};
#pragma unroll
    for (int t = 0; t < 9; ++t) {
      int dy = t / 3, dx = t % 3;
      acc0 = __builtin_amdgcn_mfma_i32_32x32x32_i8(bw[t], rin[dy][dx], acc0, 0, 0, 0);
      acc1 = __builtin_amdgcn_mfma_i32_32x32x32_i8(bw[t], rin[dy + 1][dx], acc1, 0, 0, 0);
    }
    lds_store_row(acc0, 2 * p, (unsigned)ar0 < 256u);
    lds_store_row(acc1, 2 * p + 1, (unsigned)(ar0 + 1) < 256u);
  }

  const i32x4* fpB = (const i32x4*)fragB;
#pragma unroll
  for (int t = 0; t < 9; ++t) bw[t] = fpB[t * 64 + l];
  __syncthreads();

  // ---- phase 2: layer B rows hs..hs+3 from LDS, 2 pairs ----
  int mymax = -128;
#pragma unroll 1
  for (int p = 0; p < 2; ++p) {
    i32x4 tp[4][3];
#pragma unroll
    for (int rr = 0; rr < 4; ++rr) {
      int rrel = 2 * p + rr;
#pragma unroll
      for (int dx = 0; dx < 3; ++dx)
        tp[rr][dx] = *(const i32x4*)&Lint[((rrel * 2 + hi) * PC + (w + dx)) * 4];
    }
    i32x16 acc0 = {}, acc1 = {};
#pragma unroll
    for (int t = 0; t < 9; ++t) {
      int dy = t / 3, dx = t % 3;
      if (MODE == 1) {
        acc0 = __builtin_amdgcn_mfma_i32_32x32x32_i8(tp[dy][dx], bw[t], acc0, 0, 0, 0);
        acc1 = __builtin_amdgcn_mfma_i32_32x32x32_i8(tp[dy + 1][dx], bw[t], acc1, 0, 0, 0);
      } else {
        acc0 = __builtin_amdgcn_mfma_i32_32x32x32_i8(bw[t], tp[dy][dx], acc0, 0, 0, 0);
        acc1 = __builtin_amdgcn_mfma_i32_32x32x32_i8(bw[t], tp[dy + 1][dx], acc1, 0, 0, 0);
      }
    }
    if (MODE == 0) {
#pragma unroll
      for (int rr = 0; rr < 2; ++rr) {
        const i32x16& acc = rr ? acc1 : acc0;
        int v0 = pack4(quant1(acc[0]), quant1(acc[1]), quant1(acc[2]), quant1(acc[3]));
        int v1 = pack4(quant1(acc[4]), quant1(acc[5]), quant1(acc[6]), quant1(acc[7]));
        int v2 = pack4(quant1(acc[8]), quant1(acc[9]), quant1(acc[10]), quant1(acc[11]));
        int v3 = pack4(quant1(acc[12]), quant1(acc[13]), quant1(acc[14]), quant1(acc[15]));
        i32x4 ch = half_swap(v0, v1, v2, v3, hi);
        *(i32x4*)(out + ((size_t)b * PP + (size_t)(hs + 2 * p + rr + 1) * PC + (w + 1)) * 32 + hi * 16) = ch;
      }
    } else {
      mymax = quant_max(acc1, quant_max(acc0, mymax));
    }
  }

  if (MODE == 1) {
    mymax = max(mymax, __shfl_xor(mymax, 32));
    if (hi == 0) red[wi][lo] = mymax;
    __syncthreads();
    if (tid < 32) {
      int m = -128;
#pragma unroll
      for (int r = 0; r < 8; ++r) m = max(m, red[r][tid]);
      atomicMax(&gmax[b * 32 + tid], m);
    }
  }
}

// ================= final FC =================
__global__ void fc_kernel(const int* __restrict__ gmax, const int* __restrict__ wfcq,
                          float* __restrict__ out) {
  int b = threadIdx.x;
  if (b < BB) {
    int acc = 0;
#pragma unroll
    for (int c = 0; c < 32; ++c) acc += gmax[b * 32 + c] * wfcq[c];
    int q = (acc + 63 + ((acc >> 7) & 1)) >> 7;  // rne(acc/128), exact
    q = min(127, max(-127, q));
    out[b] = (float)q * 0.0078125f;
  }
}

extern "C" void kernel_launch(void* const* d_in, const int* in_sizes, int n_in,
                              void* d_out, int out_size, void* d_ws, size_t ws_size,
                              hipStream_t stream) {
  const float* x   = (const float*)d_in[0];
  const float* w1  = (const float*)d_in[1];
  const float* wfc = (const float*)d_in[8];

  char* ws = (char*)d_ws;
  const size_t ACTP = (size_t)BB * PP * 32;  // 34,080,768 B padded act buffer
  signed char* A0    = (signed char*)ws;
  signed char* A1    = (signed char*)(ws + ACTP);
  _Float16*    pre   = (_Float16*)A1;  // 17.04 MB, dead before F0 writes A1
  _Float16*    frag1 = (_Float16*)(ws + 2 * ACTP);                 // 6144 B
  signed char* wfr   = (signed char*)(ws + 2 * ACTP + 6144);       // 6 x 9216
  int*         wfcq  = (int*)(ws + 2 * ACTP + 6144 + 6 * 9216);
  int*         gmax  = (int*)(ws + 2 * ACTP + 6144 + 6 * 9216 + 128);

  prep_kernel<<<4378, 256, 0, stream>>>(
      x, w1, (const float*)d_in[2], (const float*)d_in[3], (const float*)d_in[4],
      (const float*)d_in[5], (const float*)d_in[6], (const float*)d_in[7],
      wfc, pre, frag1, wfr, wfcq, gmax, A0);

  dim3 gridc1(2, 128, 16);  // conv1: 2-row pairs
  conv1_mfma_kernel<<<gridc1, 256, 0, stream>>>(pre, frag1, A0);
  pad_kernel<<<65, 256, 0, stream>>>(A1);  // A1 pads (after pre consumed)

  dim3 gf(64, 16);  // fused pairs: 4-row chunks, full width
  conv_fused_kernel<0><<<gf, 512, 0, stream>>>(A0, wfr + 0 * 9216, wfr + 1 * 9216, A1, nullptr);
  conv_fused_kernel<0><<<gf, 512, 0, stream>>>(A1, wfr + 2 * 9216, wfr + 3 * 9216, A0, nullptr);
  conv_fused_kernel<1><<<gf, 512, 0, stream>>>(A0, wfr + 4 * 9216, wfr + 5 * 9216, nullptr, gmax);
  fc_kernel<<<1, 64, 0, stream>>>(gmax, wfcq, (float*)d_out);
}

// Round 25
// 133.051 us; speedup vs baseline: 2.2927x; 1.0236x over previous
//
#include <hip/hip_runtime.h>

#define BB 16
#define HH 256
#define WW 256
#define PC 258                 // padded cols/rows
#define PP ((size_t)(PC * PC)) // 66564 px per padded img

typedef int i32x4 __attribute__((ext_vector_type(4)));
typedef int i32x16 __attribute__((ext_vector_type(16)));
typedef float f32x16 __attribute__((ext_vector_type(16)));
typedef _Float16 f16x8 __attribute__((ext_vector_type(8)));

// ================= fused prep =================
__global__ __launch_bounds__(256) void prep_kernel(
    const float* __restrict__ x, const float* __restrict__ w1,
    const float* __restrict__ w2, const float* __restrict__ w3,
    const float* __restrict__ w4, const float* __restrict__ w5,
    const float* __restrict__ w6, const float* __restrict__ w7,
    const float* __restrict__ wfc,
    _Float16* __restrict__ pre, _Float16* __restrict__ frag1,
    signed char* __restrict__ wfr, int* __restrict__ wfcq,
    int* __restrict__ gmax, signed char* __restrict__ A0) {
  int bid = blockIdx.x, tid = threadIdx.x;
  if (bid < 4096) {
    int px = bid * 256 + tid;  // 1,048,576 interior pixels
    int b = px >> 16, rem = px & 65535;
    int y = rem >> 8, xc = rem & 255;
    const float* xp = x + (size_t)b * 4 * 65536 + rem;
    f16x8 o;
#pragma unroll
    for (int ic = 0; ic < 4; ++ic) {
      float v = xp[ic * 65536];
      _Float16 hf = (_Float16)v;
      float r = v - (float)hf;
      o[ic * 2] = hf;
      o[ic * 2 + 1] = (_Float16)r;
    }
    *(f16x8*)(pre + ((size_t)b * PP + (size_t)(y + 1) * PC + (xc + 1)) * 8) = o;
  } else if (bid < 4312) {
    int i = (bid - 4096) * 256 + tid;  // 6 x 9216
    int layer = i / 9216, within = i - layer * 9216;
    const float* w = layer == 0 ? w2 : layer == 1 ? w3 : layer == 2 ? w4
                   : layer == 3 ? w5 : layer == 4 ? w6 : w7;
    int t = within >> 10;
    int l = (within >> 4) & 63;
    int j = within & 15;
    int ic = (l >> 5) * 16 + j;
    int oc = l & 31;
    int q = (int)rintf(w[oc * 288 + ic * 9 + t] * 128.0f);
    q = min(127, max(-127, q));
    wfr[(size_t)layer * 9216 + within] = (signed char)q;
  } else if (bid == 4312) {
    for (int p = tid; p < 384; p += 256) {
      int s = p >> 6, l = p & 63;
      int dr = s >> 1, pp = s & 1;
      int oc = l & 31, half = l >> 5;
      int dx = pp * 2 + half;
#pragma unroll
      for (int j = 0; j < 8; ++j) {
        int ic = j >> 1;
        _Float16 v = (_Float16)0.f;
        if (!(pp == 1 && half == 1)) {
          int q = (int)rintf(w1[oc * 36 + ic * 9 + dr * 3 + dx] * 128.0f);
          q = min(127, max(-127, q));
          v = (_Float16)((float)q * 0.0078125f);  // exact in fp16
        }
        frag1[s * 512 + l * 8 + j] = v;
      }
    }
    if (tid < 32) {
      int q = (int)rintf(wfc[tid] * 128.0f);
      q = min(127, max(-127, q));
      wfcq[tid] = q;
    }
    for (int i2 = tid; i2 < 512; i2 += 256) gmax[i2] = -128;
  } else {
    int idx = (bid - 4313) * 256 + tid;  // 16*1028 = 16448 pad px
    if (idx < 16448) {
      int img = idx / 1028, p = idx - img * 1028;
      int row, col;
      if (p < 258) { row = 0; col = p; }
      else if (p < 516) { row = 257; col = p - 258; }
      else { int q2 = p - 516; row = 1 + (q2 & 255); col = (q2 >> 8) ? 257 : 0; }
      size_t off = (size_t)img * PP + (size_t)row * PC + col;
      f16x8 z16 = {};
      *(f16x8*)(pre + off * 8) = z16;
      i32x4 z = {};
      ((i32x4*)(A0 + off * 32))[0] = z;
      ((i32x4*)(A0 + off * 32 + 16))[0] = z;
    }
  }
}

// zero the pads of A1 (must run AFTER conv1 consumed pre, which aliases A1)
__global__ __launch_bounds__(256) void pad_kernel(signed char* __restrict__ A1) {
  int idx = blockIdx.x * 256 + threadIdx.x;
  if (idx < 16448) {
    int img = idx / 1028, p = idx - img * 1028;
    int row, col;
    if (p < 258) { row = 0; col = p; }
    else if (p < 516) { row = 257; col = p - 258; }
    else { int q2 = p - 516; row = 1 + (q2 & 255); col = (q2 >> 8) ? 257 : 0; }
    size_t off = (size_t)img * PP + (size_t)row * PC + col;
    i32x4 z = {};
    ((i32x4*)(A1 + off * 32))[0] = z;
    ((i32x4*)(A1 + off * 32 + 16))[0] = z;
  }
}

__device__ __forceinline__ int pack4(int q0, int q1, int q2, int q3) {
  return (q0 & 255) | ((q1 & 255) << 8) | ((q2 & 255) << 16) | ((q3 & 255) << 24);
}

// Exact integer RNE: rne(a/128) = (a + 63 + ((a>>7)&1)) >> 7, bit-identical.
__device__ __forceinline__ int quant1(int a) {
  int q = (a + 63 + ((a >> 7) & 1)) >> 7;
  return min(127, max(-127, q));
}

__device__ __forceinline__ int quant_max(const i32x16& acc, int mymax) {
#pragma unroll
  for (int r = 0; r < 16; ++r) mymax = max(mymax, quant1(acc[r]));
  return mymax;
}

__device__ __forceinline__ i32x4 half_swap(int v0, int v1, int v2, int v3, int hi) {
  int s0 = hi ? v0 : v2;
  int s1 = hi ? v1 : v3;
  int r0 = __shfl_xor(s0, 32);
  int r1 = __shfl_xor(s1, 32);
  i32x4 ch;
  ch.x = hi ? r0 : v0;
  ch.y = hi ? v2 : r0;
  ch.z = hi ? r1 : v1;
  ch.w = hi ? v3 : r1;
  return ch;
}

// ================= conv1: padded pre -> padded A0 ======
__global__ __launch_bounds__(256) void conv1_mfma_kernel(
    const _Float16* __restrict__ pre, const _Float16* __restrict__ frag1,
    signed char* __restrict__ out) {
  int tid = threadIdx.x;
  int wi = tid >> 6;
  int l = tid & 63;
  int lo = l & 31;
  int hi = l >> 5;
  int b = blockIdx.z;
  int h0 = blockIdx.y * 2;
  int wbase = blockIdx.x * 128 + wi * 32;
  int w = wbase + lo;

  const f16x8* fp = (const f16x8*)frag1;
  f16x8 bf[6];
#pragma unroll
  for (int s = 0; s < 6; ++s) bf[s] = fp[s * 64 + l];

  f32x16 acc0 = {}, acc1 = {};

#pragma unroll
  for (int r = 0; r < 4; ++r) {  // input rows h0-1 .. h0+2 -> padded h0+r
    const _Float16* rp = pre + ((size_t)b * PP + (size_t)(h0 + r) * PC) * 8;
#pragma unroll
    for (int p = 0; p < 2; ++p) {
      int col = w + p * 2 + hi;  // padded col of x = w+2p+hi-1
      f16x8 av = {};
      if (!(p == 1 && hi == 1))  // k-slot pad only (not spatial)
        av = *(const f16x8*)(rp + (size_t)col * 8);
      if (r < 3) acc0 = __builtin_amdgcn_mfma_f32_32x32x16_f16(bf[r * 2 + p], av, acc0, 0, 0, 0);
      if (r > 0) acc1 = __builtin_amdgcn_mfma_f32_32x32x16_f16(bf[(r - 1) * 2 + p], av, acc1, 0, 0, 0);
    }
  }

#pragma unroll
  for (int rr = 0; rr < 2; ++rr) {
    const f32x16& acc = rr ? acc1 : acc0;
    int q[16];
#pragma unroll
    for (int r = 0; r < 16; ++r) {
      int t = (int)rintf(acc[r] * 128.0f);
      q[r] = min(127, max(-127, t));
    }
    int v0 = pack4(q[0], q[1], q[2], q[3]);
    int v1 = pack4(q[4], q[5], q[6], q[7]);
    int v2 = pack4(q[8], q[9], q[10], q[11]);
    int v3 = pack4(q[12], q[13], q[14], q[15]);
    i32x4 ch = half_swap(v0, v1, v2, v3, hi);
    *(i32x4*)(out + ((size_t)b * PP + (size_t)(h0 + rr + 1) * PC + (w + 1)) * 32 + hi * 16) = ch;
  }
}

// ================= fused mid pairs: ring-buffer phase interleave ==========
// 8 layer-B rows per block; 10 A-rows streamed through a 6-slot LDS ring.
// Iteration k (0..4): A-pair k -> ring slots (2k)%6,(2k+1)%6; ONE barrier;
// B-pair k-1 from ring. Cross-wave slot disjointness: segment [B(k-1);A(k+1)]
// writes {2k+2,2k+3}%6, reads {2k-2..2k+1}%6 - disjoint. Overcompute 1.25x
// (was 1.5x), one barrier per pair-iteration, A-loads overlap B-compute.
// A-weights persist in 36 VGPRs; B-weights reloaded per iter (laundered).
template <int MODE>
__global__ __launch_bounds__(512, 4) void conv_fused_kernel(
    const signed char* __restrict__ in, const signed char* __restrict__ fragA,
    const signed char* __restrict__ fragB, signed char* __restrict__ out,
    int* __restrict__ gmax) {
  __shared__ int Aring[6 * 2 * PC * 4];  // 49536 B
  __shared__ int red[8][32];

  int tid = threadIdx.x;
  int wi = tid >> 6;
  int l = tid & 63;
  int lo = l & 31;
  int hi = l >> 5;
  int b = blockIdx.y;
  int hs = blockIdx.x * 8;  // layer-B output rows hs..hs+7
  int w = wi * 32 + lo;

  // zero ring col halo (cols 0 and 257 of each of 12 subrows)
  if (tid < 24) {
    int rr = tid >> 2, half = (tid >> 1) & 1, cs = tid & 1;
    i32x4 z = {};
    *(i32x4*)&Aring[((rr * 2 + half) * PC + (cs ? 257 : 0)) * 4] = z;
  }

  const i32x4* fpA = (const i32x4*)fragA;
  i32x4 bwA[9];
#pragma unroll
  for (int t = 0; t < 9; ++t) bwA[t] = fpA[t * 64 + l];

  int lanep = (w << 5) + (hi << 4);

  auto rowptr = [&](int ar) -> const signed char* {
    int prow = min(max(ar + 1, 0), 257);  // clamps land in zero halo
    return in + ((size_t)b * PP + (size_t)prow * PC) * 32 + lanep;
  };

  auto ring_store = [&](const i32x16& acc, int slot, bool valid) {
    int v0 = pack4(quant1(acc[0]), quant1(acc[1]), quant1(acc[2]), quant1(acc[3]));
    int v1 = pack4(quant1(acc[4]), quant1(acc[5]), quant1(acc[6]), quant1(acc[7]));
    int v2 = pack4(quant1(acc[8]), quant1(acc[9]), quant1(acc[10]), quant1(acc[11]));
    int v3 = pack4(quant1(acc[12]), quant1(acc[13]), quant1(acc[14]), quant1(acc[15]));
    i32x4 ch = half_swap(v0, v1, v2, v3, hi);
    if (!valid) ch = i32x4{};
    *(i32x4*)&Aring[((slot * 2 + hi) * PC + (w + 1)) * 4] = ch;
  };

  int mymax = -128;

#pragma unroll 1
  for (int k = 0; k < 5; ++k) {
    // ---- A-pair k: rows ar0, ar0+1 ----
    int ar0 = hs - 1 + 2 * k;
    i32x4 rin[4][3];
#pragma unroll
    for (int rr = 0; rr < 4; ++rr) {
      const signed char* rp = rowptr(ar0 - 1 + rr);
#pragma unroll
      for (int dx = 0; dx < 3; ++dx) rin[rr][dx] = *(const i32x4*)(rp + dx * 32);
    }
    i32x16 acc0 = {}, acc1 = {};
#pragma unroll
    for (int t = 0; t < 9; ++t) {
      int dy = t / 3, dx = t % 3;
      acc0 = __builtin_amdgcn_mfma_i32_32x32x32_i8(bwA[t], rin[dy][dx], acc0, 0, 0, 0);
      acc1 = __builtin_amdgcn_mfma_i32_32x32x32_i8(bwA[t], rin[dy + 1][dx], acc1, 0, 0, 0);
    }
    ring_store(acc0, (2 * k) % 6, (unsigned)ar0 < 256u);
    ring_store(acc1, (2 * k + 1) % 6, (unsigned)(ar0 + 1) < 256u);

    __syncthreads();

    // ---- B-pair k-1: rows hs+2(k-1), +1 ----
    if (k >= 1) {
      int j = k - 1;
      int pz = 0;
      asm volatile("" : "+v"(pz));  // keep bwB loads inside the loop
      const i32x4* fpB = (const i32x4*)fragB;
      i32x4 bwB[9];
#pragma unroll
      for (int t = 0; t < 9; ++t) bwB[t] = fpB[t * 64 + l + pz];

      i32x4 tp[4][3];
#pragma unroll
      for (int rr = 0; rr < 4; ++rr) {
        int slot = (2 * j + rr) % 6;  // A-row hs+2j-1+rr
#pragma unroll
        for (int dx = 0; dx < 3; ++dx)
          tp[rr][dx] = *(const i32x4*)&Aring[((slot * 2 + hi) * PC + (w + dx)) * 4];
      }
      i32x16 c0 = {}, c1 = {};
#pragma unroll
      for (int t = 0; t < 9; ++t) {
        int dy = t / 3, dx = t % 3;
        if (MODE == 1) {
          c0 = __builtin_amdgcn_mfma_i32_32x32x32_i8(tp[dy][dx], bwB[t], c0, 0, 0, 0);
          c1 = __builtin_amdgcn_mfma_i32_32x32x32_i8(tp[dy + 1][dx], bwB[t], c1, 0, 0, 0);
        } else {
          c0 = __builtin_amdgcn_mfma_i32_32x32x32_i8(bwB[t], tp[dy][dx], c0, 0, 0, 0);
          c1 = __builtin_amdgcn_mfma_i32_32x32x32_i8(bwB[t], tp[dy + 1][dx], c1, 0, 0, 0);
        }
      }
      if (MODE == 0) {
#pragma unroll
        for (int rr = 0; rr < 2; ++rr) {
          const i32x16& acc = rr ? c1 : c0;
          int v0 = pack4(quant1(acc[0]), quant1(acc[1]), quant1(acc[2]), quant1(acc[3]));
          int v1 = pack4(quant1(acc[4]), quant1(acc[5]), quant1(acc[6]), quant1(acc[7]));
          int v2 = pack4(quant1(acc[8]), quant1(acc[9]), quant1(acc[10]), quant1(acc[11]));
          int v3 = pack4(quant1(acc[12]), quant1(acc[13]), quant1(acc[14]), quant1(acc[15]));
          i32x4 ch = half_swap(v0, v1, v2, v3, hi);
          *(i32x4*)(out + ((size_t)b * PP + (size_t)(hs + 2 * j + rr + 1) * PC + (w + 1)) * 32 + hi * 16) = ch;
        }
      } else {
        mymax = quant_max(c1, quant_max(c0, mymax));
      }
    }
  }

  if (MODE == 1) {
    mymax = max(mymax, __shfl_xor(mymax, 32));
    if (hi == 0) red[wi][lo] = mymax;
    __syncthreads();
    if (tid < 32) {
      int m = -128;
#pragma unroll
      for (int r = 0; r < 8; ++r) m = max(m, red[r][tid]);
      atomicMax(&gmax[b * 32 + tid], m);
    }
  }
}

// ================= final FC =================
__global__ void fc_kernel(const int* __restrict__ gmax, const int* __restrict__ wfcq,
                          float* __restrict__ out) {
  int b = threadIdx.x;
  if (b < BB) {
    int acc = 0;
#pragma unroll
    for (int c = 0; c < 32; ++c) acc += gmax[b * 32 + c] * wfcq[c];
    int q = (acc + 63 + ((acc >> 7) & 1)) >> 7;  // rne(acc/128), exact
    q = min(127, max(-127, q));
    out[b] = (float)q * 0.0078125f;
  }
}

extern "C" void kernel_launch(void* const* d_in, const int* in_sizes, int n_in,
                              void* d_out, int out_size, void* d_ws, size_t ws_size,
                              hipStream_t stream) {
  const float* x   = (const float*)d_in[0];
  const float* w1  = (const float*)d_in[1];
  const float* wfc = (const float*)d_in[8];

  char* ws = (char*)d_ws;
  const size_t ACTP = (size_t)BB * PP * 32;  // 34,080,768 B padded act buffer
  signed char* A0    = (signed char*)ws;
  signed char* A1    = (signed char*)(ws + ACTP);
  _Float16*    pre   = (_Float16*)A1;  // dead before F0 writes A1
  _Float16*    frag1 = (_Float16*)(ws + 2 * ACTP);                 // 6144 B
  signed char* wfr   = (signed char*)(ws + 2 * ACTP + 6144);       // 6 x 9216
  int*         wfcq  = (int*)(ws + 2 * ACTP + 6144 + 6 * 9216);
  int*         gmax  = (int*)(ws + 2 * ACTP + 6144 + 6 * 9216 + 128);

  prep_kernel<<<4378, 256, 0, stream>>>(
      x, w1, (const float*)d_in[2], (const float*)d_in[3], (const float*)d_in[4],
      (const float*)d_in[5], (const float*)d_in[6], (const float*)d_in[7],
      wfc, pre, frag1, wfr, wfcq, gmax, A0);

  dim3 gridc1(2, 128, 16);  // conv1: 2-row pairs
  conv1_mfma_kernel<<<gridc1, 256, 0, stream>>>(pre, frag1, A0);
  pad_kernel<<<65, 256, 0, stream>>>(A1);  // A1 pads (after pre consumed)

  dim3 gf(32, 16);  // fused pairs: 8-row chunks, full width, 2 blocks/CU
  conv_fused_kernel<0><<<gf, 512, 0, stream>>>(A0, wfr + 0 * 9216, wfr + 1 * 9216, A1, nullptr);
  conv_fused_kernel<0><<<gf, 512, 0, stream>>>(A1, wfr + 2 * 9216, wfr + 3 * 9216, A0, nullptr);
  conv_fused_kernel<1><<<gf, 512, 0, stream>>>(A0, wfr + 4 * 9216, wfr + 5 * 9216, nullptr, gmax);
  fc_kernel<<<1, 64, 0, stream>>>(gmax, wfcq, (float*)d_out);
}